// Round 9
// baseline (237.166 us; speedup 1.0000x reference)
//
#include <hip/hip_runtime.h>
#include <hip/hip_bf16.h>

#define EPS 1e-5f
#define SCALE 0.17677669529663687f    // 32^-0.5
#define QSCALE 0.25500526817095634f   // SCALE * log2(e): attn uses exp2

typedef __attribute__((ext_vector_type(8))) short bf16x8;
typedef __attribute__((ext_vector_type(4))) float f32x4;
typedef __attribute__((ext_vector_type(8))) unsigned short u16x8;

__device__ __forceinline__ unsigned short f2bf(float x) {
  union { float f; unsigned int u; } a; a.f = x;
  unsigned int r = a.u + 0x7FFFu + ((a.u >> 16) & 1u);
  return (unsigned short)(r >> 16);
}
__device__ __forceinline__ float bf2f(unsigned short u) {
  union { unsigned int u; float f; } a; a.u = ((unsigned int)u) << 16;
  return a.f;
}

// single-instruction v_exp_f32 (2^x).
__device__ __forceinline__ float fexp2(float x) {
#if __has_builtin(__builtin_amdgcn_exp2f)
  return __builtin_amdgcn_exp2f(x);
#else
  float r; asm("v_exp_f32 %0, %1" : "=v"(r) : "v"(x)); return r;
#endif
}

// async global->LDS, 16 B per lane; lds base wave-uniform, HW writes lane i
// at ldsbase + i*16 (guide §5 / m97).
__device__ __forceinline__ void gload_lds16(const void* g, void* l) {
  __builtin_amdgcn_global_load_lds(
      (const __attribute__((address_space(1))) unsigned int*)g,
      (__attribute__((address_space(3))) unsigned int*)l, 16, 0, 0);
}

// pack high halves of two f32 -> [hi16(b) : hi16(a)] (truncation, 1 v_perm)
__device__ __forceinline__ unsigned int pack_bf_trunc(float a, float b) {
  return __builtin_amdgcn_perm(__float_as_uint(b), __float_as_uint(a), 0x07060302u);
}

// ---------------------------------------------------------------------------
// Cast qkv_w (1024x512) and proj_w (512x512) fp32 -> bf16, same layout.
// ---------------------------------------------------------------------------
__global__ __launch_bounds__(256) void cast_w_kernel(
    const float* __restrict__ qw, const float* __restrict__ pw,
    short* __restrict__ wq, short* __restrict__ wp) {
  int idx = blockIdx.x * 256 + threadIdx.x;
  const float4* src;
  ushort4* dst;
  if (idx < 131072) {
    src = (const float4*)qw + idx;
    dst = (ushort4*)wq + idx;
  } else {
    src = (const float4*)pw + (idx - 131072);
    dst = (ushort4*)wp + (idx - 131072);
  }
  float4 v = *src;
  ushort4 u;
  u.x = f2bf(v.x); u.y = f2bf(v.y); u.z = f2bf(v.z); u.w = f2bf(v.w);
  *dst = u;
}

// ---------------------------------------------------------------------------
// Transpose-cast X (B,512,1600) fp32 -> XT (B,1600,512) bf16. 64x64 LDS tile.
// ---------------------------------------------------------------------------
__global__ __launch_bounds__(256) void transpose_cast_kernel(
    const float* __restrict__ X, short* __restrict__ XT) {
  __shared__ unsigned short T[64][72];
  const int b = blockIdx.z, c0 = blockIdx.x * 64, n0 = blockIdx.y * 64;
  const int t = threadIdx.x, nl = t & 63, w = t >> 6;
#pragma unroll
  for (int ci = 0; ci < 16; ++ci) {
    int cl = ci * 4 + w;
    T[nl][cl] = f2bf(X[((size_t)(b * 512 + c0 + cl)) * 1600 + n0 + nl]);
  }
  __syncthreads();
  const int n2 = t >> 2, cg = (t & 3) * 16;
  unsigned short* o = (unsigned short*)XT + ((size_t)(b * 1600 + n0 + n2)) * 512 + c0 + cg;
  *(u16x8*)&o[0] = *(const u16x8*)&T[n2][cg];
  *(u16x8*)&o[8] = *(const u16x8*)&T[n2][cg + 8];
}

// ---------------------------------------------------------------------------
// Transpose bf16 (B,512,1600) -> (B,1600,512). Same 64x64 LDS tile pattern.
// ---------------------------------------------------------------------------
__global__ __launch_bounds__(256) void transpose16_kernel(
    const short* __restrict__ S, short* __restrict__ D) {
  __shared__ unsigned short T[64][72];
  const int b = blockIdx.z, c0 = blockIdx.x * 64, n0 = blockIdx.y * 64;
  const int t = threadIdx.x, nl = t & 63, w = t >> 6;
  const unsigned short* Sp = (const unsigned short*)S;
#pragma unroll
  for (int ci = 0; ci < 16; ++ci) {
    int cl = ci * 4 + w;
    T[nl][cl] = Sp[((size_t)(b * 512 + c0 + cl)) * 1600 + n0 + nl];
  }
  __syncthreads();
  const int n2 = t >> 2, cg = (t & 3) * 16;
  unsigned short* o = (unsigned short*)D + ((size_t)(b * 1600 + n0 + n2)) * 512 + c0 + cg;
  *(u16x8*)&o[0] = *(const u16x8*)&T[n2][cg];
  *(u16x8*)&o[8] = *(const u16x8*)&T[n2][cg + 8];
}

// ---------------------------------------------------------------------------
// QKV GEMM v5: m97 structure; q pre-scaled by QSCALE for exp2 domain.
// V is written to BOTH layouts:
//   vb[b][c][n]            -> for pe_kernel (fast contiguous gather there)
//   vp[bh][kb=n/8][d][n%8] -> for attn (PV B-fragment = one 16B load,
//                             4x256B coalesced per instruction)
// ---------------------------------------------------------------------------
__global__ __launch_bounds__(256) void qkv_mfma_kernel(
    const short* __restrict__ XT, const short* __restrict__ WQ,
    const float* __restrict__ gamma, const float* __restrict__ beta,
    const float* __restrict__ mean, const float* __restrict__ var,
    short* __restrict__ qT, short* __restrict__ kT,
    short* __restrict__ vb, short* __restrict__ vp) {
  __shared__ __align__(16) unsigned short As[128 * 32];
  __shared__ __align__(16) unsigned short Bs[128 * 32];

  const int t = threadIdx.x, w = t >> 6, lane = t & 63;
  const int quad = lane >> 4, l16 = lane & 15;
  const int wr = w >> 1, wc = w & 1;
  const int ngt = blockIdx.x, h = blockIdx.y;
  const int o0 = h * 128, ng0 = ngt * 128;

  const int srow = lane >> 2;
  const int sseg = (lane & 3) * 8;

  f32x4 acc[4][4];
#pragma unroll
  for (int mi = 0; mi < 4; ++mi)
#pragma unroll
    for (int nj = 0; nj < 4; ++nj) { acc[mi][nj][0]=0.f; acc[mi][nj][1]=0.f; acc[mi][nj][2]=0.f; acc[mi][nj][3]=0.f; }

  for (int kt = 0; kt < 16; ++kt) {
    const int c0 = kt * 32;
    if (kt) __syncthreads();
#pragma unroll
    for (int r = 0; r < 2; ++r) {
      const int row = (r * 4 + w) * 16 + srow;
      gload_lds16(WQ + (size_t)(o0 + row) * 512 + c0 + sseg, As + (r * 4 + w) * 512);
      gload_lds16(XT + (size_t)(ng0 + row) * 512 + c0 + sseg, Bs + (r * 4 + w) * 512);
    }
    __syncthreads();
    bf16x8 af[4], bfr[4];
#pragma unroll
    for (int i = 0; i < 4; ++i) {
      af[i]  = *(const bf16x8*)&As[(wr * 64 + i * 16 + l16) * 32 + quad * 8];
      bfr[i] = *(const bf16x8*)&Bs[(wc * 64 + i * 16 + l16) * 32 + quad * 8];
    }
#pragma unroll
    for (int mi = 0; mi < 4; ++mi)
#pragma unroll
      for (int nj = 0; nj < 4; ++nj)
        acc[mi][nj] = __builtin_amdgcn_mfma_f32_16x16x32_bf16(af[mi], bfr[nj], acc[mi][nj], 0, 0, 0);
  }

  const int ng_base = ng0 + wc * 64;
#pragma unroll
  for (int mi = 0; mi < 4; ++mi) {
    const int ol = wr * 64 + mi * 16 + quad * 4;
    const int ob = o0 + ol;
    float inv[4], add[4];
#pragma unroll
    for (int r = 0; r < 4; ++r) {
      inv[r] = gamma[ob + r] * rsqrtf(var[ob + r] + EPS);
      add[r] = beta[ob + r] - mean[ob + r] * inv[r];
    }
    const int region = wr * 2 + (mi >> 1);   // 0=q, 1=k, 2/3=v
    if (region == 0) {
      const int kk = mi * 16 + quad * 4;
#pragma unroll
      for (int nj = 0; nj < 4; ++nj) {
        int ng = ng_base + nj * 16 + l16;
        int b = ng / 1600, n = ng - b * 1600;
        ushort4 u;
        u.x = f2bf((acc[mi][nj][0] * inv[0] + add[0]) * QSCALE);
        u.y = f2bf((acc[mi][nj][1] * inv[1] + add[1]) * QSCALE);
        u.z = f2bf((acc[mi][nj][2] * inv[2] + add[2]) * QSCALE);
        u.w = f2bf((acc[mi][nj][3] * inv[3] + add[3]) * QSCALE);
        *(ushort4*)&qT[((size_t)(b * 8 + h) * 1600 + n) * 32 + kk] = u;
      }
    } else if (region == 1) {
      const int kk = (mi - 2) * 16 + quad * 4;
#pragma unroll
      for (int nj = 0; nj < 4; ++nj) {
        int ng = ng_base + nj * 16 + l16;
        int b = ng / 1600, n = ng - b * 1600;
        ushort4 u;
        u.x = f2bf(acc[mi][nj][0] * inv[0] + add[0]);
        u.y = f2bf(acc[mi][nj][1] * inv[1] + add[1]);
        u.z = f2bf(acc[mi][nj][2] * inv[2] + add[2]);
        u.w = f2bf(acc[mi][nj][3] * inv[3] + add[3]);
        *(ushort4*)&kT[((size_t)(b * 8 + h) * 1600 + n) * 32 + kk] = u;
      }
    } else {
      const int ch = h * 64 + (ol - 64);    // global channel (for vb)
      const int d0 = ol - 64;               // d within head (for vp)
#pragma unroll
      for (int nj = 0; nj < 4; ++nj) {
        int ng = ng_base + nj * 16 + l16;
        int b = ng / 1600, n = ng - b * 1600;
        unsigned short val[4];
#pragma unroll
        for (int r = 0; r < 4; ++r)
          val[r] = f2bf(acc[mi][nj][r] * inv[r] + add[r]);
#pragma unroll
        for (int r = 0; r < 4; ++r)
          ((unsigned short*)vb)[((size_t)(b * 512 + ch + r)) * 1600 + n] = val[r];
        unsigned short* dst = (unsigned short*)vp +
            ((size_t)(b * 8 + h) * 200 + (n >> 3)) * 512 + d0 * 8 + (n & 7);
#pragma unroll
        for (int r = 0; r < 4; ++r)
          dst[r * 8] = val[r];
      }
    }
  }
}

// ---------------------------------------------------------------------------
// MFMA flash attention v14 = v11 with prefetch distance 2 (three static
// named buffer sets A/B/C, loop unrolled x3, all compile-time indices).
// Rationale: v11's 1-deep prefetch leaves one COMP (~140 cyc) between load
// issue and use; L2 latency is ~200-400 cyc, so ~50% of per-tile time was
// still latency stall (per-tile-slot ~286 cyc vs ~140 issue). Distance 2
// gives two COMP bodies (~280 cyc) of cover. Zero LDS, zero barriers,
// K-row-permuted QK^T A-operand, V' single-16B B-fragments, VALU den.
// ---------------------------------------------------------------------------
__global__ __launch_bounds__(256) void attn_mfma_kernel(
    const short* __restrict__ qT, const short* __restrict__ kT,
    const short* __restrict__ vp, short* __restrict__ ybf) {
  const int N = 1600;
  const int t = threadIdx.x;
  const int w = t >> 6, lane = t & 63, quad = lane >> 4, l16 = lane & 15;
  const int bh = blockIdx.x, b = bh >> 3, h = bh & 7;
  const int n0w = blockIdx.y * 128 + w * 32;   // this wave's 32 queries
  if (n0w >= 1600) return;                     // tail waves (no barriers -> ok)

  const unsigned short* qTb = (const unsigned short*)qT + (size_t)bh * N * 32;
  const unsigned short* kTb = (const unsigned short*)kT + (size_t)bh * N * 32;
  const unsigned short* vpb = (const unsigned short*)vp + (size_t)bh * 102400;

  // B-fragments of Q: col=l16 -> query, k=quad*8+j (full KEY_DIM=32)
  const bf16x8 qf0 = *(const bf16x8*)(qTb + (size_t)(n0w + l16) * 32 + quad * 8);
  const bf16x8 qf1 = *(const bf16x8*)(qTb + (size_t)(n0w + 16 + l16) * 32 + quad * 8);

  f32x4 acc0[4], acc1[4];
#pragma unroll
  for (int i = 0; i < 4; ++i) {
    acc0[i][0]=0.f; acc0[i][1]=0.f; acc0[i][2]=0.f; acc0[i][3]=0.f;
    acc1[i][0]=0.f; acc1[i][1]=0.f; acc1[i][2]=0.f; acc1[i][3]=0.f;
  }
  float den0 = 0.f, den1 = 0.f;
  const f32x4 zero4 = {0.f, 0.f, 0.f, 0.f};

  // K A-fragment row permutation: row l16 -> key 2*(l16&~3)+(l16&3)
  const int kperm = ((l16 & 12) << 1) + (l16 & 3);
  const unsigned short* kp = kTb + (size_t)kperm * 32 + quad * 8;
  // V' fragment base: lane (q,l16) reads keys (mt*4+q)*8..+7 at d=i*16+l16
  const unsigned short* vq = vpb + (size_t)quad * 512 + l16 * 8;

#define LOADT(MT, K0, K1, V0, V1, V2, V3) \
  { \
    const unsigned short* kpm_ = kp + (size_t)(MT) * 1024; \
    const unsigned short* vqm_ = vq + (size_t)(MT) * 2048; \
    K0 = *(const bf16x8*)kpm_; \
    K1 = *(const bf16x8*)(kpm_ + 128); \
    V0 = *(const bf16x8*)(vqm_); \
    V1 = *(const bf16x8*)(vqm_ + 128); \
    V2 = *(const bf16x8*)(vqm_ + 256); \
    V3 = *(const bf16x8*)(vqm_ + 384); \
  }

#define COMP(K0, K1, V0, V1, V2, V3) \
  { \
    f32x4 s0_ = __builtin_amdgcn_mfma_f32_16x16x32_bf16(K0, qf0, zero4, 0, 0, 0); \
    f32x4 s1_ = __builtin_amdgcn_mfma_f32_16x16x32_bf16(K1, qf0, zero4, 0, 0, 0); \
    f32x4 t0_ = __builtin_amdgcn_mfma_f32_16x16x32_bf16(K0, qf1, zero4, 0, 0, 0); \
    f32x4 t1_ = __builtin_amdgcn_mfma_f32_16x16x32_bf16(K1, qf1, zero4, 0, 0, 0); \
    float a0_ = fexp2(s0_[0]), a1_ = fexp2(s0_[1]), a2_ = fexp2(s0_[2]), a3_ = fexp2(s0_[3]); \
    float a4_ = fexp2(s1_[0]), a5_ = fexp2(s1_[1]), a6_ = fexp2(s1_[2]), a7_ = fexp2(s1_[3]); \
    float b0_ = fexp2(t0_[0]), b1_ = fexp2(t0_[1]), b2_ = fexp2(t0_[2]), b3_ = fexp2(t0_[3]); \
    float b4_ = fexp2(t1_[0]), b5_ = fexp2(t1_[1]), b6_ = fexp2(t1_[2]), b7_ = fexp2(t1_[3]); \
    den0 += ((a0_ + a1_) + (a2_ + a3_)) + ((a4_ + a5_) + (a6_ + a7_)); \
    den1 += ((b0_ + b1_) + (b2_ + b3_)) + ((b4_ + b5_) + (b6_ + b7_)); \
    union { bf16x8 v; uint4 u; } pk0_, pk1_; \
    pk0_.u.x = pack_bf_trunc(a0_, a1_); pk0_.u.y = pack_bf_trunc(a2_, a3_); \
    pk0_.u.z = pack_bf_trunc(a4_, a5_); pk0_.u.w = pack_bf_trunc(a6_, a7_); \
    pk1_.u.x = pack_bf_trunc(b0_, b1_); pk1_.u.y = pack_bf_trunc(b2_, b3_); \
    pk1_.u.z = pack_bf_trunc(b4_, b5_); pk1_.u.w = pack_bf_trunc(b6_, b7_); \
    acc0[0] = __builtin_amdgcn_mfma_f32_16x16x32_bf16(pk0_.v, V0, acc0[0], 0, 0, 0); \
    acc1[0] = __builtin_amdgcn_mfma_f32_16x16x32_bf16(pk1_.v, V0, acc1[0], 0, 0, 0); \
    acc0[1] = __builtin_amdgcn_mfma_f32_16x16x32_bf16(pk0_.v, V1, acc0[1], 0, 0, 0); \
    acc1[1] = __builtin_amdgcn_mfma_f32_16x16x32_bf16(pk1_.v, V1, acc1[1], 0, 0, 0); \
    acc0[2] = __builtin_amdgcn_mfma_f32_16x16x32_bf16(pk0_.v, V2, acc0[2], 0, 0, 0); \
    acc1[2] = __builtin_amdgcn_mfma_f32_16x16x32_bf16(pk1_.v, V2, acc1[2], 0, 0, 0); \
    acc0[3] = __builtin_amdgcn_mfma_f32_16x16x32_bf16(pk0_.v, V3, acc0[3], 0, 0, 0); \
    acc1[3] = __builtin_amdgcn_mfma_f32_16x16x32_bf16(pk1_.v, V3, acc1[3], 0, 0, 0); \
  }

  bf16x8 ak0, ak1, av0, av1, av2, av3;
  bf16x8 bk0, bk1, bv0, bv1, bv2, bv3;
  bf16x8 ck0, ck1, cv0, cv1, cv2, cv3;
  LOADT(0, ak0, ak1, av0, av1, av2, av3);
  LOADT(1, bk0, bk1, bv0, bv1, bv2, bv3);

  // 16 iterations x 3 tiles = tiles 0..47; loads reach tile 49.
#pragma unroll 1
  for (int it = 0; it < 16; ++it) {
    const int mt = it * 3;
    LOADT(mt + 2, ck0, ck1, cv0, cv1, cv2, cv3);
    COMP(ak0, ak1, av0, av1, av2, av3);
    LOADT(mt + 3, ak0, ak1, av0, av1, av2, av3);
    COMP(bk0, bk1, bv0, bv1, bv2, bv3);
    LOADT(mt + 4, bk0, bk1, bv0, bv1, bv2, bv3);
    COMP(ck0, ck1, cv0, cv1, cv2, cv3);
  }
  // Epilogue: tiles 48 (in A) and 49 (in B).
  COMP(ak0, ak1, av0, av1, av2, av3);
  COMP(bk0, bk1, bv0, bv1, bv2, bv3);
#undef COMP
#undef LOADT

  // den(lane q,l16) covers keys of quad q only -> reduce across quads
  den0 += __shfl_xor(den0, 16, 64);
  den0 += __shfl_xor(den0, 32, 64);
  den1 += __shfl_xor(den1, 16, 64);
  den1 += __shfl_xor(den1, 32, 64);
  const float rden0 = 1.f / den0;   // for query n0w + l16
  const float rden1 = 1.f / den1;   // for query n0w + 16 + l16
  // acc rows are queries quad*4+r -> fetch their rden from lanes 0..15
  float dv0[4], dv1[4];
#pragma unroll
  for (int r = 0; r < 4; ++r) {
    dv0[r] = __shfl(rden0, quad * 4 + r, 64);
    dv1[r] = __shfl(rden1, quad * 4 + r, 64);
  }

  unsigned short* yb = (unsigned short*)ybf + ((size_t)b * 512 + h * 64) * N;
#pragma unroll
  for (int i = 0; i < 4; ++i) {
    const size_t rowo = (size_t)(i * 16 + l16) * N;
    ushort4 o4;
    o4.x = f2bf(acc0[i][0] * dv0[0]);
    o4.y = f2bf(acc0[i][1] * dv0[1]);
    o4.z = f2bf(acc0[i][2] * dv0[2]);
    o4.w = f2bf(acc0[i][3] * dv0[3]);
    *(ushort4*)&yb[rowo + n0w + quad * 4] = o4;
    o4.x = f2bf(acc1[i][0] * dv1[0]);
    o4.y = f2bf(acc1[i][1] * dv1[1]);
    o4.z = f2bf(acc1[i][2] * dv1[2]);
    o4.w = f2bf(acc1[i][3] * dv1[3]);
    *(ushort4*)&yb[rowo + n0w + 16 + quad * 4] = o4;
  }
}

// ---------------------------------------------------------------------------
// PE v4 (round-0 version): bf16 y in, LDS-staged dw3x3 + BN + add, bf16 out.
// Reads vb[b][c][n] (contiguous runs).
// ---------------------------------------------------------------------------
__global__ __launch_bounds__(256) void pe_kernel(
    const short* __restrict__ Ybf, const short* __restrict__ VB,
    const float* __restrict__ pw,
    const float* __restrict__ gamma, const float* __restrict__ beta,
    const float* __restrict__ mean, const float* __restrict__ var,
    short* __restrict__ YB) {
  __shared__ __align__(16) unsigned short V[4 * 42 * 56];
  __shared__ float wlds[36];
  __shared__ float invs[4], adds[4];

  const int t = threadIdx.x;
  const int b = blockIdx.y, c0 = blockIdx.x * 4;

  const u16x8 z = {0, 0, 0, 0, 0, 0, 0, 0};
  for (int k = t; k < 1176; k += 256)
    *(u16x8*)&V[k * 8] = z;
  if (t < 36) wlds[t] = pw[c0 * 9 + t];
  if (t < 4) {
    int c = c0 + t;
    float inv = gamma[c] * rsqrtf(var[c] + EPS);
    invs[t] = inv;
    adds[t] = beta[c] - mean[c] * inv;
  }
  __syncthreads();

  for (int u = t; u < 800; u += 256) {
    int ch = u / 200, j = u - ch * 200;
    int row = j / 5, col8 = (j - row * 5) * 8;
    u16x8 d = *(const u16x8*)((const unsigned short*)VB +
        ((size_t)(b * 512 + c0 + ch) * 1600 + row * 40 + col8));
    *(u16x8*)&V[ch * 2352 + (row + 1) * 56 + 8 + col8] = d;
  }
  __syncthreads();

#pragma unroll 1
  for (int k = 0; k < 25; ++k) {
    int o = k * 256 + t;
    int ch = o / 1600, n = o - ch * 1600;
    int hh = n / 40, ww = n - hh * 40;
    const unsigned short* Vc = &V[ch * 2352 + (hh + 1) * 56 + 8 + ww];
    const float* wk = &wlds[ch * 9];
    float s = 0.f;
#pragma unroll
    for (int dy = 0; dy < 3; ++dy)
#pragma unroll
      for (int dx = 0; dx < 3; ++dx)
        s += wk[dy * 3 + dx] * bf2f(Vc[(dy - 1) * 56 + (dx - 1)]);
    size_t idx = (size_t)(b * 512 + c0 + ch) * 1600 + n;
    float val = bf2f(((const unsigned short*)Ybf)[idx]) + s * invs[ch] + adds[ch];
    YB[idx] = (short)f2bf(val);
  }
}

// ---------------------------------------------------------------------------
// Proj GEMM v3 (m97 structure, unchanged).
// ---------------------------------------------------------------------------
__global__ __launch_bounds__(256) void proj_mfma_kernel(
    const short* __restrict__ YT, const short* __restrict__ WP,
    const float* __restrict__ gamma, const float* __restrict__ beta,
    const float* __restrict__ mean, const float* __restrict__ var,
    float* __restrict__ OUT) {
  __shared__ __align__(16) unsigned short As[64 * 32];
  __shared__ __align__(16) unsigned short Bs[128 * 32];

  const int t = threadIdx.x, w = t >> 6, lane = t & 63;
  const int quad = lane >> 4, l16 = lane & 15;
  const int wr = w >> 1, wc = w & 1;
  const int ngt = blockIdx.x;
  const int o0 = blockIdx.y * 64;
  const int ng0 = ngt * 128;

  const int srow = lane >> 2;
  const int sseg = (lane & 3) * 8;

  f32x4 acc[2][4];
#pragma unroll
  for (int mi = 0; mi < 2; ++mi)
#pragma unroll
    for (int nj = 0; nj < 4; ++nj) { acc[mi][nj][0]=0.f; acc[mi][nj][1]=0.f; acc[mi][nj][2]=0.f; acc[mi][nj][3]=0.f; }

  for (int kt = 0; kt < 16; ++kt) {
    const int c0 = kt * 32;
    if (kt) __syncthreads();
    {
      const int row = w * 16 + srow;
      gload_lds16(WP + (size_t)(o0 + row) * 512 + c0 + sseg, As + w * 512);
    }
#pragma unroll
    for (int r = 0; r < 2; ++r) {
      const int row = (r * 4 + w) * 16 + srow;
      gload_lds16(YT + (size_t)(ng0 + row) * 512 + c0 + sseg, Bs + (r * 4 + w) * 512);
    }
    __syncthreads();
    bf16x8 af[2], bfr[4];
#pragma unroll
    for (int i = 0; i < 2; ++i)
      af[i] = *(const bf16x8*)&As[(wr * 32 + i * 16 + l16) * 32 + quad * 8];
#pragma unroll
    for (int i = 0; i < 4; ++i)
      bfr[i] = *(const bf16x8*)&Bs[(wc * 64 + i * 16 + l16) * 32 + quad * 8];
#pragma unroll
    for (int mi = 0; mi < 2; ++mi)
#pragma unroll
      for (int nj = 0; nj < 4; ++nj)
        acc[mi][nj] = __builtin_amdgcn_mfma_f32_16x16x32_bf16(af[mi], bfr[nj], acc[mi][nj], 0, 0, 0);
  }

  const int ng_base = ng0 + wc * 64;
#pragma unroll
  for (int mi = 0; mi < 2; ++mi) {
    const int ob = o0 + wr * 32 + mi * 16 + quad * 4;
    float inv[4], add[4];
#pragma unroll
    for (int r = 0; r < 4; ++r) {
      inv[r] = gamma[ob + r] * rsqrtf(var[ob + r] + EPS);
      add[r] = beta[ob + r] - mean[ob + r] * inv[r];
    }
#pragma unroll
    for (int nj = 0; nj < 4; ++nj) {
      int ng = ng_base + nj * 16 + l16;
      int b = ng / 1600, n = ng - b * 1600;
#pragma unroll
      for (int r = 0; r < 4; ++r)
        OUT[((size_t)(b * 512 + ob + r)) * 1600 + n] = acc[mi][nj][r] * inv[r] + add[r];
    }
  }
}

// ---------------------------------------------------------------------------
extern "C" void kernel_launch(void* const* d_in, const int* in_sizes, int n_in,
                              void* d_out, int out_size, void* d_ws, size_t ws_size,
                              hipStream_t stream) {
  const float* x          = (const float*)d_in[0];
  const float* qkv_w      = (const float*)d_in[1];
  const float* qkv_gamma  = (const float*)d_in[2];
  const float* qkv_beta   = (const float*)d_in[3];
  const float* qkv_mean   = (const float*)d_in[4];
  const float* qkv_var    = (const float*)d_in[5];
  const float* pe_w       = (const float*)d_in[6];
  const float* pe_gamma   = (const float*)d_in[7];
  const float* pe_beta    = (const float*)d_in[8];
  const float* pe_mean    = (const float*)d_in[9];
  const float* pe_var     = (const float*)d_in[10];
  const float* proj_w     = (const float*)d_in[11];
  const float* proj_gamma = (const float*)d_in[12];
  const float* proj_beta  = (const float*)d_in[13];
  const float* proj_mean  = (const float*)d_in[14];
  const float* proj_var   = (const float*)d_in[15];
  float* out = (float*)d_out;

  float* ws_a = (float*)d_ws;
  short* ybf_attn = (short*)d_ws;                 // 6.55M shorts used
  short* vp   = ybf_attn + (size_t)6553600;       // dead half of 26.2MB region
  short* qT   = (short*)(ws_a + (size_t)6553600);
  short* kT   = qT + (size_t)3276800;
  short* vb   = kT + (size_t)3276800;
  short* xT   = vb + (size_t)6553600;
  short* wq   = xT + (size_t)6553600;
  short* wp   = wq + (size_t)524288;
  short* yT   = xT;
  short* ybf_pe = qT;

  cast_w_kernel<<<768, 256, 0, stream>>>(qkv_w, proj_w, wq, wp);
  {
    dim3 grid(8, 25, 8), block(256);
    transpose_cast_kernel<<<grid, block, 0, stream>>>(x, xT);
  }
  {
    dim3 grid(100, 8), block(256);
    qkv_mfma_kernel<<<grid, block, 0, stream>>>(
        xT, wq, qkv_gamma, qkv_beta, qkv_mean, qkv_var, qT, kT, vb, vp);
  }
  {
    dim3 grid(64, 13), block(256);
    attn_mfma_kernel<<<grid, block, 0, stream>>>(qT, kT, vp, ybf_attn);
  }
  {
    dim3 grid(128, 8), block(256);
    pe_kernel<<<grid, block, 0, stream>>>(
        ybf_attn, vb, pe_w, pe_gamma, pe_beta, pe_mean, pe_var, ybf_pe);
  }
  {
    dim3 grid(8, 25, 8), block(256);
    transpose16_kernel<<<grid, block, 0, stream>>>(ybf_pe, yT);
  }
  {
    dim3 grid(100, 8), block(256);
    proj_mfma_kernel<<<grid, block, 0, stream>>>(
        yT, wp, proj_gamma, proj_beta, proj_mean, proj_var, out);
  }
}

// Round 10
// 229.839 us; speedup vs baseline: 1.0319x; 1.0319x over previous
//
#include <hip/hip_runtime.h>
#include <hip/hip_bf16.h>

#define EPS 1e-5f
#define SCALE 0.17677669529663687f    // 32^-0.5
#define QSCALE 0.25500526817095634f   // SCALE * log2(e): attn uses exp2

typedef __attribute__((ext_vector_type(8))) short bf16x8;
typedef __attribute__((ext_vector_type(4))) float f32x4;
typedef __attribute__((ext_vector_type(8))) unsigned short u16x8;

__device__ __forceinline__ unsigned short f2bf(float x) {
  union { float f; unsigned int u; } a; a.f = x;
  unsigned int r = a.u + 0x7FFFu + ((a.u >> 16) & 1u);
  return (unsigned short)(r >> 16);
}
__device__ __forceinline__ float bf2f(unsigned short u) {
  union { unsigned int u; float f; } a; a.u = ((unsigned int)u) << 16;
  return a.f;
}

// single-instruction v_exp_f32 (2^x).
__device__ __forceinline__ float fexp2(float x) {
#if __has_builtin(__builtin_amdgcn_exp2f)
  return __builtin_amdgcn_exp2f(x);
#else
  float r; asm("v_exp_f32 %0, %1" : "=v"(r) : "v"(x)); return r;
#endif
}

// async global->LDS, 16 B per lane; lds base wave-uniform, HW writes lane i
// at ldsbase + i*16 (guide §5 / m97).
__device__ __forceinline__ void gload_lds16(const void* g, void* l) {
  __builtin_amdgcn_global_load_lds(
      (const __attribute__((address_space(1))) unsigned int*)g,
      (__attribute__((address_space(3))) unsigned int*)l, 16, 0, 0);
}

// pack high halves of two f32 -> [hi16(b) : hi16(a)] (truncation, 1 v_perm)
__device__ __forceinline__ unsigned int pack_bf_trunc(float a, float b) {
  return __builtin_amdgcn_perm(__float_as_uint(b), __float_as_uint(a), 0x07060302u);
}

// ---------------------------------------------------------------------------
// Cast qkv_w (1024x512) and proj_w (512x512) fp32 -> bf16, same layout.
// ---------------------------------------------------------------------------
__global__ __launch_bounds__(256) void cast_w_kernel(
    const float* __restrict__ qw, const float* __restrict__ pw,
    short* __restrict__ wq, short* __restrict__ wp) {
  int idx = blockIdx.x * 256 + threadIdx.x;
  const float4* src;
  ushort4* dst;
  if (idx < 131072) {
    src = (const float4*)qw + idx;
    dst = (ushort4*)wq + idx;
  } else {
    src = (const float4*)pw + (idx - 131072);
    dst = (ushort4*)wp + (idx - 131072);
  }
  float4 v = *src;
  ushort4 u;
  u.x = f2bf(v.x); u.y = f2bf(v.y); u.z = f2bf(v.z); u.w = f2bf(v.w);
  *dst = u;
}

// ---------------------------------------------------------------------------
// Transpose-cast X (B,512,1600) fp32 -> XT (B,1600,512) bf16. 64x64 LDS tile.
// ---------------------------------------------------------------------------
__global__ __launch_bounds__(256) void transpose_cast_kernel(
    const float* __restrict__ X, short* __restrict__ XT) {
  __shared__ unsigned short T[64][72];
  const int b = blockIdx.z, c0 = blockIdx.x * 64, n0 = blockIdx.y * 64;
  const int t = threadIdx.x, nl = t & 63, w = t >> 6;
#pragma unroll
  for (int ci = 0; ci < 16; ++ci) {
    int cl = ci * 4 + w;
    T[nl][cl] = f2bf(X[((size_t)(b * 512 + c0 + cl)) * 1600 + n0 + nl]);
  }
  __syncthreads();
  const int n2 = t >> 2, cg = (t & 3) * 16;
  unsigned short* o = (unsigned short*)XT + ((size_t)(b * 1600 + n0 + n2)) * 512 + c0 + cg;
  *(u16x8*)&o[0] = *(const u16x8*)&T[n2][cg];
  *(u16x8*)&o[8] = *(const u16x8*)&T[n2][cg + 8];
}

// ---------------------------------------------------------------------------
// Transpose bf16 (B,512,1600) -> (B,1600,512). Same 64x64 LDS tile pattern.
// ---------------------------------------------------------------------------
__global__ __launch_bounds__(256) void transpose16_kernel(
    const short* __restrict__ S, short* __restrict__ D) {
  __shared__ unsigned short T[64][72];
  const int b = blockIdx.z, c0 = blockIdx.x * 64, n0 = blockIdx.y * 64;
  const int t = threadIdx.x, nl = t & 63, w = t >> 6;
  const unsigned short* Sp = (const unsigned short*)S;
#pragma unroll
  for (int ci = 0; ci < 16; ++ci) {
    int cl = ci * 4 + w;
    T[nl][cl] = Sp[((size_t)(b * 512 + c0 + cl)) * 1600 + n0 + nl];
  }
  __syncthreads();
  const int n2 = t >> 2, cg = (t & 3) * 16;
  unsigned short* o = (unsigned short*)D + ((size_t)(b * 1600 + n0 + n2)) * 512 + c0 + cg;
  *(u16x8*)&o[0] = *(const u16x8*)&T[n2][cg];
  *(u16x8*)&o[8] = *(const u16x8*)&T[n2][cg + 8];
}

// ---------------------------------------------------------------------------
// QKV GEMM v6: m97 structure; q pre-scaled by QSCALE for exp2 domain.
// V outputs:
//   vb[b][c][n]  -> direct stores (32B runs), as in the round-0 baseline.
//   vp[bh][kb][d][8] -> NEW: staged in LDS Vs[128 n][68 d] then written
//     cooperatively as 1024 consecutive 16B chunks (fully coalesced 1KB
//     runs). Replaces the 2B/16B-stride scatter that cost ~10us.
// ---------------------------------------------------------------------------
__global__ __launch_bounds__(256) void qkv_mfma_kernel(
    const short* __restrict__ XT, const short* __restrict__ WQ,
    const float* __restrict__ gamma, const float* __restrict__ beta,
    const float* __restrict__ mean, const float* __restrict__ var,
    short* __restrict__ qT, short* __restrict__ kT,
    short* __restrict__ vb, short* __restrict__ vp) {
  __shared__ __align__(16) unsigned short As[128 * 32];
  __shared__ __align__(16) unsigned short Bs[128 * 32];
  __shared__ __align__(16) unsigned short Vs[128 * 68];   // [n_local][d], pad 68

  const int t = threadIdx.x, w = t >> 6, lane = t & 63;
  const int quad = lane >> 4, l16 = lane & 15;
  const int wr = w >> 1, wc = w & 1;
  const int ngt = blockIdx.x, h = blockIdx.y;
  const int o0 = h * 128, ng0 = ngt * 128;

  const int srow = lane >> 2;
  const int sseg = (lane & 3) * 8;

  f32x4 acc[4][4];
#pragma unroll
  for (int mi = 0; mi < 4; ++mi)
#pragma unroll
    for (int nj = 0; nj < 4; ++nj) { acc[mi][nj][0]=0.f; acc[mi][nj][1]=0.f; acc[mi][nj][2]=0.f; acc[mi][nj][3]=0.f; }

  for (int kt = 0; kt < 16; ++kt) {
    const int c0 = kt * 32;
    if (kt) __syncthreads();
#pragma unroll
    for (int r = 0; r < 2; ++r) {
      const int row = (r * 4 + w) * 16 + srow;
      gload_lds16(WQ + (size_t)(o0 + row) * 512 + c0 + sseg, As + (r * 4 + w) * 512);
      gload_lds16(XT + (size_t)(ng0 + row) * 512 + c0 + sseg, Bs + (r * 4 + w) * 512);
    }
    __syncthreads();
    bf16x8 af[4], bfr[4];
#pragma unroll
    for (int i = 0; i < 4; ++i) {
      af[i]  = *(const bf16x8*)&As[(wr * 64 + i * 16 + l16) * 32 + quad * 8];
      bfr[i] = *(const bf16x8*)&Bs[(wc * 64 + i * 16 + l16) * 32 + quad * 8];
    }
#pragma unroll
    for (int mi = 0; mi < 4; ++mi)
#pragma unroll
      for (int nj = 0; nj < 4; ++nj)
        acc[mi][nj] = __builtin_amdgcn_mfma_f32_16x16x32_bf16(af[mi], bfr[nj], acc[mi][nj], 0, 0, 0);
  }

  const int ng_base = ng0 + wc * 64;
#pragma unroll
  for (int mi = 0; mi < 4; ++mi) {
    const int ol = wr * 64 + mi * 16 + quad * 4;
    const int ob = o0 + ol;
    float inv[4], add[4];
#pragma unroll
    for (int r = 0; r < 4; ++r) {
      inv[r] = gamma[ob + r] * rsqrtf(var[ob + r] + EPS);
      add[r] = beta[ob + r] - mean[ob + r] * inv[r];
    }
    const int region = wr * 2 + (mi >> 1);   // 0=q, 1=k, 2/3=v
    if (region == 0) {
      const int kk = mi * 16 + quad * 4;
#pragma unroll
      for (int nj = 0; nj < 4; ++nj) {
        int ng = ng_base + nj * 16 + l16;
        int b = ng / 1600, n = ng - b * 1600;
        ushort4 u;
        u.x = f2bf((acc[mi][nj][0] * inv[0] + add[0]) * QSCALE);
        u.y = f2bf((acc[mi][nj][1] * inv[1] + add[1]) * QSCALE);
        u.z = f2bf((acc[mi][nj][2] * inv[2] + add[2]) * QSCALE);
        u.w = f2bf((acc[mi][nj][3] * inv[3] + add[3]) * QSCALE);
        *(ushort4*)&qT[((size_t)(b * 8 + h) * 1600 + n) * 32 + kk] = u;
      }
    } else if (region == 1) {
      const int kk = (mi - 2) * 16 + quad * 4;
#pragma unroll
      for (int nj = 0; nj < 4; ++nj) {
        int ng = ng_base + nj * 16 + l16;
        int b = ng / 1600, n = ng - b * 1600;
        ushort4 u;
        u.x = f2bf(acc[mi][nj][0] * inv[0] + add[0]);
        u.y = f2bf(acc[mi][nj][1] * inv[1] + add[1]);
        u.z = f2bf(acc[mi][nj][2] * inv[2] + add[2]);
        u.w = f2bf(acc[mi][nj][3] * inv[3] + add[3]);
        *(ushort4*)&kT[((size_t)(b * 8 + h) * 1600 + n) * 32 + kk] = u;
      }
    } else {
      const int ch = h * 64 + (ol - 64);    // global channel (for vb)
      const int d0 = ol - 64;               // d within head: mi*16+quad*4
#pragma unroll
      for (int nj = 0; nj < 4; ++nj) {
        int ng = ng_base + nj * 16 + l16;
        int n_local = ng - ng0;             // wc*64 + nj*16 + l16
        int b = ng / 1600, n = ng - b * 1600;
        unsigned short val[4];
#pragma unroll
        for (int r = 0; r < 4; ++r)
          val[r] = f2bf(acc[mi][nj][r] * inv[r] + add[r]);
        // vb direct (baseline path, 32B runs)
#pragma unroll
        for (int r = 0; r < 4; ++r)
          ((unsigned short*)vb)[((size_t)(b * 512 + ch + r)) * 1600 + n] = val[r];
        // LDS stage for the coalesced vp write (ushort2 pairs, 4B aligned)
#pragma unroll
        for (int k = 0; k < 2; ++k) {
          unsigned int pk = (unsigned int)val[2 * k] |
                            ((unsigned int)val[2 * k + 1] << 16);
          *(unsigned int*)&Vs[n_local * 68 + d0 + 2 * k] = pk;
        }
      }
    }
  }

  __syncthreads();
  // Cooperative vp write: 1024 chunks (16 kb x 64 d); thread t emits 4.
  // Consecutive threads -> consecutive d -> consecutive 16B -> 1KB runs.
#pragma unroll
  for (int cc = 0; cc < 4; ++cc) {
    const int c = cc * 256 + t;
    const int kbl = c >> 6, d = c & 63;
    const int n_gl = ng0 + kbl * 8;
    const int b = n_gl / 1600, nn = n_gl - b * 1600;
    union { unsigned short u[8]; u16x8 v; } pk;
#pragma unroll
    for (int j = 0; j < 8; ++j)
      pk.u[j] = Vs[(kbl * 8 + j) * 68 + d];
    *(u16x8*)((unsigned short*)vp +
        ((size_t)(b * 8 + h) * 200 + (nn >> 3)) * 512 + d * 8) = pk.v;
  }
}

// ---------------------------------------------------------------------------
// MFMA flash attention v11 (best measured: 63.0us): 32 q/wave, zero LDS /
// zero barriers, K-row-permuted QK^T A-operand, V' single-16B B-fragments,
// VALU den, static 1-tile-ahead register prefetch.
// ---------------------------------------------------------------------------
__global__ __launch_bounds__(256) void attn_mfma_kernel(
    const short* __restrict__ qT, const short* __restrict__ kT,
    const short* __restrict__ vp, short* __restrict__ ybf) {
  const int N = 1600;
  const int t = threadIdx.x;
  const int w = t >> 6, lane = t & 63, quad = lane >> 4, l16 = lane & 15;
  const int bh = blockIdx.x, b = bh >> 3, h = bh & 7;
  const int n0w = blockIdx.y * 128 + w * 32;   // this wave's 32 queries
  if (n0w >= 1600) return;                     // tail waves (no barriers -> ok)

  const unsigned short* qTb = (const unsigned short*)qT + (size_t)bh * N * 32;
  const unsigned short* kTb = (const unsigned short*)kT + (size_t)bh * N * 32;
  const unsigned short* vpb = (const unsigned short*)vp + (size_t)bh * 102400;

  // B-fragments of Q: col=l16 -> query, k=quad*8+j (full KEY_DIM=32)
  const bf16x8 qf0 = *(const bf16x8*)(qTb + (size_t)(n0w + l16) * 32 + quad * 8);
  const bf16x8 qf1 = *(const bf16x8*)(qTb + (size_t)(n0w + 16 + l16) * 32 + quad * 8);

  f32x4 acc0[4], acc1[4];
#pragma unroll
  for (int i = 0; i < 4; ++i) {
    acc0[i][0]=0.f; acc0[i][1]=0.f; acc0[i][2]=0.f; acc0[i][3]=0.f;
    acc1[i][0]=0.f; acc1[i][1]=0.f; acc1[i][2]=0.f; acc1[i][3]=0.f;
  }
  float den0 = 0.f, den1 = 0.f;
  const f32x4 zero4 = {0.f, 0.f, 0.f, 0.f};

  // K A-fragment row permutation: row l16 -> key 2*(l16&~3)+(l16&3)
  const int kperm = ((l16 & 12) << 1) + (l16 & 3);
  const unsigned short* kp = kTb + (size_t)kperm * 32 + quad * 8;
  // V' fragment base: lane (q,l16) reads keys (mt*4+q)*8..+7 at d=i*16+l16
  const unsigned short* vq = vpb + (size_t)quad * 512 + l16 * 8;

  // Prologue: tile 0 into the "c" buffer set.
  bf16x8 ck0 = *(const bf16x8*)kp;
  bf16x8 ck1 = *(const bf16x8*)(kp + 128);
  bf16x8 cv0 = *(const bf16x8*)(vq);
  bf16x8 cv1 = *(const bf16x8*)(vq + 128);
  bf16x8 cv2 = *(const bf16x8*)(vq + 256);
  bf16x8 cv3 = *(const bf16x8*)(vq + 384);
  bf16x8 nk0, nk1, nv0, nv1, nv2, nv3;

  // Body: prefetch tile NXT into the N-set, compute the C-set's tile.
#define ATTN_BODY(NXT, CK0, CK1, CV0, CV1, CV2, CV3, NK0, NK1, NV0, NV1, NV2, NV3) \
  { \
    const int nx_ = (NXT) < 50 ? (NXT) : 0; \
    const unsigned short* kpn_ = kp + (size_t)nx_ * 1024; \
    const unsigned short* vqn_ = vq + (size_t)nx_ * 2048; \
    NK0 = *(const bf16x8*)kpn_; \
    NK1 = *(const bf16x8*)(kpn_ + 128); \
    NV0 = *(const bf16x8*)(vqn_); \
    NV1 = *(const bf16x8*)(vqn_ + 128); \
    NV2 = *(const bf16x8*)(vqn_ + 256); \
    NV3 = *(const bf16x8*)(vqn_ + 384); \
    f32x4 s0_ = __builtin_amdgcn_mfma_f32_16x16x32_bf16(CK0, qf0, zero4, 0, 0, 0); \
    f32x4 s1_ = __builtin_amdgcn_mfma_f32_16x16x32_bf16(CK1, qf0, zero4, 0, 0, 0); \
    f32x4 t0_ = __builtin_amdgcn_mfma_f32_16x16x32_bf16(CK0, qf1, zero4, 0, 0, 0); \
    f32x4 t1_ = __builtin_amdgcn_mfma_f32_16x16x32_bf16(CK1, qf1, zero4, 0, 0, 0); \
    float a0_ = fexp2(s0_[0]), a1_ = fexp2(s0_[1]), a2_ = fexp2(s0_[2]), a3_ = fexp2(s0_[3]); \
    float a4_ = fexp2(s1_[0]), a5_ = fexp2(s1_[1]), a6_ = fexp2(s1_[2]), a7_ = fexp2(s1_[3]); \
    float b0_ = fexp2(t0_[0]), b1_ = fexp2(t0_[1]), b2_ = fexp2(t0_[2]), b3_ = fexp2(t0_[3]); \
    float b4_ = fexp2(t1_[0]), b5_ = fexp2(t1_[1]), b6_ = fexp2(t1_[2]), b7_ = fexp2(t1_[3]); \
    den0 += ((a0_ + a1_) + (a2_ + a3_)) + ((a4_ + a5_) + (a6_ + a7_)); \
    den1 += ((b0_ + b1_) + (b2_ + b3_)) + ((b4_ + b5_) + (b6_ + b7_)); \
    union { bf16x8 v; uint4 u; } pk0_, pk1_; \
    pk0_.u.x = pack_bf_trunc(a0_, a1_); pk0_.u.y = pack_bf_trunc(a2_, a3_); \
    pk0_.u.z = pack_bf_trunc(a4_, a5_); pk0_.u.w = pack_bf_trunc(a6_, a7_); \
    pk1_.u.x = pack_bf_trunc(b0_, b1_); pk1_.u.y = pack_bf_trunc(b2_, b3_); \
    pk1_.u.z = pack_bf_trunc(b4_, b5_); pk1_.u.w = pack_bf_trunc(b6_, b7_); \
    acc0[0] = __builtin_amdgcn_mfma_f32_16x16x32_bf16(pk0_.v, CV0, acc0[0], 0, 0, 0); \
    acc1[0] = __builtin_amdgcn_mfma_f32_16x16x32_bf16(pk1_.v, CV0, acc1[0], 0, 0, 0); \
    acc0[1] = __builtin_amdgcn_mfma_f32_16x16x32_bf16(pk0_.v, CV1, acc0[1], 0, 0, 0); \
    acc1[1] = __builtin_amdgcn_mfma_f32_16x16x32_bf16(pk1_.v, CV1, acc1[1], 0, 0, 0); \
    acc0[2] = __builtin_amdgcn_mfma_f32_16x16x32_bf16(pk0_.v, CV2, acc0[2], 0, 0, 0); \
    acc1[2] = __builtin_amdgcn_mfma_f32_16x16x32_bf16(pk1_.v, CV2, acc1[2], 0, 0, 0); \
    acc0[3] = __builtin_amdgcn_mfma_f32_16x16x32_bf16(pk0_.v, CV3, acc0[3], 0, 0, 0); \
    acc1[3] = __builtin_amdgcn_mfma_f32_16x16x32_bf16(pk1_.v, CV3, acc1[3], 0, 0, 0); \
  }

#pragma unroll 1
  for (int mt2 = 0; mt2 < 25; ++mt2) {
    ATTN_BODY(2 * mt2 + 1, ck0, ck1, cv0, cv1, cv2, cv3, nk0, nk1, nv0, nv1, nv2, nv3);
    ATTN_BODY(2 * mt2 + 2, nk0, nk1, nv0, nv1, nv2, nv3, ck0, ck1, cv0, cv1, cv2, cv3);
  }
#undef ATTN_BODY

  // den(lane q,l16) covers keys of quad q only -> reduce across quads
  den0 += __shfl_xor(den0, 16, 64);
  den0 += __shfl_xor(den0, 32, 64);
  den1 += __shfl_xor(den1, 16, 64);
  den1 += __shfl_xor(den1, 32, 64);
  const float rden0 = 1.f / den0;   // for query n0w + l16
  const float rden1 = 1.f / den1;   // for query n0w + 16 + l16
  // acc rows are queries quad*4+r -> fetch their rden from lanes 0..15
  float dv0[4], dv1[4];
#pragma unroll
  for (int r = 0; r < 4; ++r) {
    dv0[r] = __shfl(rden0, quad * 4 + r, 64);
    dv1[r] = __shfl(rden1, quad * 4 + r, 64);
  }

  unsigned short* yb = (unsigned short*)ybf + ((size_t)b * 512 + h * 64) * N;
#pragma unroll
  for (int i = 0; i < 4; ++i) {
    const size_t rowo = (size_t)(i * 16 + l16) * N;
    ushort4 o4;
    o4.x = f2bf(acc0[i][0] * dv0[0]);
    o4.y = f2bf(acc0[i][1] * dv0[1]);
    o4.z = f2bf(acc0[i][2] * dv0[2]);
    o4.w = f2bf(acc0[i][3] * dv0[3]);
    *(ushort4*)&yb[rowo + n0w + quad * 4] = o4;
    o4.x = f2bf(acc1[i][0] * dv1[0]);
    o4.y = f2bf(acc1[i][1] * dv1[1]);
    o4.z = f2bf(acc1[i][2] * dv1[2]);
    o4.w = f2bf(acc1[i][3] * dv1[3]);
    *(ushort4*)&yb[rowo + n0w + 16 + quad * 4] = o4;
  }
}

// ---------------------------------------------------------------------------
// PE v4 (round-0 version): bf16 y in, LDS-staged dw3x3 + BN + add, bf16 out.
// Reads vb[b][c][n] (contiguous runs).
// ---------------------------------------------------------------------------
__global__ __launch_bounds__(256) void pe_kernel(
    const short* __restrict__ Ybf, const short* __restrict__ VB,
    const float* __restrict__ pw,
    const float* __restrict__ gamma, const float* __restrict__ beta,
    const float* __restrict__ mean, const float* __restrict__ var,
    short* __restrict__ YB) {
  __shared__ __align__(16) unsigned short V[4 * 42 * 56];
  __shared__ float wlds[36];
  __shared__ float invs[4], adds[4];

  const int t = threadIdx.x;
  const int b = blockIdx.y, c0 = blockIdx.x * 4;

  const u16x8 z = {0, 0, 0, 0, 0, 0, 0, 0};
  for (int k = t; k < 1176; k += 256)
    *(u16x8*)&V[k * 8] = z;
  if (t < 36) wlds[t] = pw[c0 * 9 + t];
  if (t < 4) {
    int c = c0 + t;
    float inv = gamma[c] * rsqrtf(var[c] + EPS);
    invs[t] = inv;
    adds[t] = beta[c] - mean[c] * inv;
  }
  __syncthreads();

  for (int u = t; u < 800; u += 256) {
    int ch = u / 200, j = u - ch * 200;
    int row = j / 5, col8 = (j - row * 5) * 8;
    u16x8 d = *(const u16x8*)((const unsigned short*)VB +
        ((size_t)(b * 512 + c0 + ch) * 1600 + row * 40 + col8));
    *(u16x8*)&V[ch * 2352 + (row + 1) * 56 + 8 + col8] = d;
  }
  __syncthreads();

#pragma unroll 1
  for (int k = 0; k < 25; ++k) {
    int o = k * 256 + t;
    int ch = o / 1600, n = o - ch * 1600;
    int hh = n / 40, ww = n - hh * 40;
    const unsigned short* Vc = &V[ch * 2352 + (hh + 1) * 56 + 8 + ww];
    const float* wk = &wlds[ch * 9];
    float s = 0.f;
#pragma unroll
    for (int dy = 0; dy < 3; ++dy)
#pragma unroll
      for (int dx = 0; dx < 3; ++dx)
        s += wk[dy * 3 + dx] * bf2f(Vc[(dy - 1) * 56 + (dx - 1)]);
    size_t idx = (size_t)(b * 512 + c0 + ch) * 1600 + n;
    float val = bf2f(((const unsigned short*)Ybf)[idx]) + s * invs[ch] + adds[ch];
    YB[idx] = (short)f2bf(val);
  }
}

// ---------------------------------------------------------------------------
// Proj GEMM v3 (m97 structure, unchanged).
// ---------------------------------------------------------------------------
__global__ __launch_bounds__(256) void proj_mfma_kernel(
    const short* __restrict__ YT, const short* __restrict__ WP,
    const float* __restrict__ gamma, const float* __restrict__ beta,
    const float* __restrict__ mean, const float* __restrict__ var,
    float* __restrict__ OUT) {
  __shared__ __align__(16) unsigned short As[64 * 32];
  __shared__ __align__(16) unsigned short Bs[128 * 32];

  const int t = threadIdx.x, w = t >> 6, lane = t & 63;
  const int quad = lane >> 4, l16 = lane & 15;
  const int wr = w >> 1, wc = w & 1;
  const int ngt = blockIdx.x;
  const int o0 = blockIdx.y * 64;
  const int ng0 = ngt * 128;

  const int srow = lane >> 2;
  const int sseg = (lane & 3) * 8;

  f32x4 acc[2][4];
#pragma unroll
  for (int mi = 0; mi < 2; ++mi)
#pragma unroll
    for (int nj = 0; nj < 4; ++nj) { acc[mi][nj][0]=0.f; acc[mi][nj][1]=0.f; acc[mi][nj][2]=0.f; acc[mi][nj][3]=0.f; }

  for (int kt = 0; kt < 16; ++kt) {
    const int c0 = kt * 32;
    if (kt) __syncthreads();
    {
      const int row = w * 16 + srow;
      gload_lds16(WP + (size_t)(o0 + row) * 512 + c0 + sseg, As + w * 512);
    }
#pragma unroll
    for (int r = 0; r < 2; ++r) {
      const int row = (r * 4 + w) * 16 + srow;
      gload_lds16(YT + (size_t)(ng0 + row) * 512 + c0 + sseg, Bs + (r * 4 + w) * 512);
    }
    __syncthreads();
    bf16x8 af[2], bfr[4];
#pragma unroll
    for (int i = 0; i < 2; ++i)
      af[i] = *(const bf16x8*)&As[(wr * 32 + i * 16 + l16) * 32 + quad * 8];
#pragma unroll
    for (int i = 0; i < 4; ++i)
      bfr[i] = *(const bf16x8*)&Bs[(wc * 64 + i * 16 + l16) * 32 + quad * 8];
#pragma unroll
    for (int mi = 0; mi < 2; ++mi)
#pragma unroll
      for (int nj = 0; nj < 4; ++nj)
        acc[mi][nj] = __builtin_amdgcn_mfma_f32_16x16x32_bf16(af[mi], bfr[nj], acc[mi][nj], 0, 0, 0);
  }

  const int ng_base = ng0 + wc * 64;
#pragma unroll
  for (int mi = 0; mi < 2; ++mi) {
    const int ob = o0 + wr * 32 + mi * 16 + quad * 4;
    float inv[4], add[4];
#pragma unroll
    for (int r = 0; r < 4; ++r) {
      inv[r] = gamma[ob + r] * rsqrtf(var[ob + r] + EPS);
      add[r] = beta[ob + r] - mean[ob + r] * inv[r];
    }
#pragma unroll
    for (int nj = 0; nj < 4; ++nj) {
      int ng = ng_base + nj * 16 + l16;
      int b = ng / 1600, n = ng - b * 1600;
#pragma unroll
      for (int r = 0; r < 4; ++r)
        OUT[((size_t)(b * 512 + ob + r)) * 1600 + n] = acc[mi][nj][r] * inv[r] + add[r];
    }
  }
}

// ---------------------------------------------------------------------------
extern "C" void kernel_launch(void* const* d_in, const int* in_sizes, int n_in,
                              void* d_out, int out_size, void* d_ws, size_t ws_size,
                              hipStream_t stream) {
  const float* x          = (const float*)d_in[0];
  const float* qkv_w      = (const float*)d_in[1];
  const float* qkv_gamma  = (const float*)d_in[2];
  const float* qkv_beta   = (const float*)d_in[3];
  const float* qkv_mean   = (const float*)d_in[4];
  const float* qkv_var    = (const float*)d_in[5];
  const float* pe_w       = (const float*)d_in[6];
  const float* pe_gamma   = (const float*)d_in[7];
  const float* pe_beta    = (const float*)d_in[8];
  const float* pe_mean    = (const float*)d_in[9];
  const float* pe_var     = (const float*)d_in[10];
  const float* proj_w     = (const float*)d_in[11];
  const float* proj_gamma = (const float*)d_in[12];
  const float* proj_beta  = (const float*)d_in[13];
  const float* proj_mean  = (const float*)d_in[14];
  const float* proj_var   = (const float*)d_in[15];
  float* out = (float*)d_out;

  float* ws_a = (float*)d_ws;
  short* ybf_attn = (short*)d_ws;                 // 6.55M shorts used
  short* vp   = ybf_attn + (size_t)6553600;       // dead half of 26.2MB region
  short* qT   = (short*)(ws_a + (size_t)6553600);
  short* kT   = qT + (size_t)3276800;
  short* vb   = kT + (size_t)3276800;
  short* xT   = vb + (size_t)6553600;
  short* wq   = xT + (size_t)6553600;
  short* wp   = wq + (size_t)524288;
  short* yT   = xT;
  short* ybf_pe = qT;

  cast_w_kernel<<<768, 256, 0, stream>>>(qkv_w, proj_w, wq, wp);
  {
    dim3 grid(8, 25, 8), block(256);
    transpose_cast_kernel<<<grid, block, 0, stream>>>(x, xT);
  }
  {
    dim3 grid(100, 8), block(256);
    qkv_mfma_kernel<<<grid, block, 0, stream>>>(
        xT, wq, qkv_gamma, qkv_beta, qkv_mean, qkv_var, qT, kT, vb, vp);
  }
  {
    dim3 grid(64, 13), block(256);
    attn_mfma_kernel<<<grid, block, 0, stream>>>(qT, kT, vp, ybf_attn);
  }
  {
    dim3 grid(128, 8), block(256);
    pe_kernel<<<grid, block, 0, stream>>>(
        ybf_attn, vb, pe_w, pe_gamma, pe_beta, pe_mean, pe_var, ybf_pe);
  }
  {
    dim3 grid(8, 25, 8), block(256);
    transpose16_kernel<<<grid, block, 0, stream>>>(ybf_pe, yT);
  }
  {
    dim3 grid(100, 8), block(256);
    proj_mfma_kernel<<<grid, block, 0, stream>>>(
        yT, wp, proj_gamma, proj_beta, proj_mean, proj_var, out);
  }
}

// Round 11
// 226.087 us; speedup vs baseline: 1.0490x; 1.0166x over previous
//
#include <hip/hip_runtime.h>
#include <hip/hip_bf16.h>

#define EPS 1e-5f
#define SCALE 0.17677669529663687f    // 32^-0.5
#define QSCALE 0.25500526817095634f   // SCALE * log2(e): attn uses exp2

typedef __attribute__((ext_vector_type(8))) short bf16x8;
typedef __attribute__((ext_vector_type(4))) float f32x4;
typedef __attribute__((ext_vector_type(8))) unsigned short u16x8;

__device__ __forceinline__ unsigned short f2bf(float x) {
  union { float f; unsigned int u; } a; a.f = x;
  unsigned int r = a.u + 0x7FFFu + ((a.u >> 16) & 1u);
  return (unsigned short)(r >> 16);
}
__device__ __forceinline__ float bf2f(unsigned short u) {
  union { unsigned int u; float f; } a; a.u = ((unsigned int)u) << 16;
  return a.f;
}

// single-instruction v_exp_f32 (2^x).
__device__ __forceinline__ float fexp2(float x) {
#if __has_builtin(__builtin_amdgcn_exp2f)
  return __builtin_amdgcn_exp2f(x);
#else
  float r; asm("v_exp_f32 %0, %1" : "=v"(r) : "v"(x)); return r;
#endif
}

// async global->LDS, 16 B per lane; lds base wave-uniform, HW writes lane i
// at ldsbase + i*16 (guide §5 / m97).
__device__ __forceinline__ void gload_lds16(const void* g, void* l) {
  __builtin_amdgcn_global_load_lds(
      (const __attribute__((address_space(1))) unsigned int*)g,
      (__attribute__((address_space(3))) unsigned int*)l, 16, 0, 0);
}

// pack high halves of two f32 -> [hi16(b) : hi16(a)] (truncation, 1 v_perm)
__device__ __forceinline__ unsigned int pack_bf_trunc(float a, float b) {
  return __builtin_amdgcn_perm(__float_as_uint(b), __float_as_uint(a), 0x07060302u);
}

// ---------------------------------------------------------------------------
// Cast qkv_w (1024x512) and proj_w (512x512) fp32 -> bf16, same layout.
// ---------------------------------------------------------------------------
__global__ __launch_bounds__(256) void cast_w_kernel(
    const float* __restrict__ qw, const float* __restrict__ pw,
    short* __restrict__ wq, short* __restrict__ wp) {
  int idx = blockIdx.x * 256 + threadIdx.x;
  const float4* src;
  ushort4* dst;
  if (idx < 131072) {
    src = (const float4*)qw + idx;
    dst = (ushort4*)wq + idx;
  } else {
    src = (const float4*)pw + (idx - 131072);
    dst = (ushort4*)wp + (idx - 131072);
  }
  float4 v = *src;
  ushort4 u;
  u.x = f2bf(v.x); u.y = f2bf(v.y); u.z = f2bf(v.z); u.w = f2bf(v.w);
  *dst = u;
}

// ---------------------------------------------------------------------------
// Transpose-cast X (B,512,1600) fp32 -> XT (B,1600,512) bf16. 64x64 LDS tile.
// ---------------------------------------------------------------------------
__global__ __launch_bounds__(256) void transpose_cast_kernel(
    const float* __restrict__ X, short* __restrict__ XT) {
  __shared__ unsigned short T[64][72];
  const int b = blockIdx.z, c0 = blockIdx.x * 64, n0 = blockIdx.y * 64;
  const int t = threadIdx.x, nl = t & 63, w = t >> 6;
#pragma unroll
  for (int ci = 0; ci < 16; ++ci) {
    int cl = ci * 4 + w;
    T[nl][cl] = f2bf(X[((size_t)(b * 512 + c0 + cl)) * 1600 + n0 + nl]);
  }
  __syncthreads();
  const int n2 = t >> 2, cg = (t & 3) * 16;
  unsigned short* o = (unsigned short*)XT + ((size_t)(b * 1600 + n0 + n2)) * 512 + c0 + cg;
  *(u16x8*)&o[0] = *(const u16x8*)&T[n2][cg];
  *(u16x8*)&o[8] = *(const u16x8*)&T[n2][cg + 8];
}

// ---------------------------------------------------------------------------
// Transpose bf16 (B,512,1600) -> (B,1600,512). Same 64x64 LDS tile pattern.
// ---------------------------------------------------------------------------
__global__ __launch_bounds__(256) void transpose16_kernel(
    const short* __restrict__ S, short* __restrict__ D) {
  __shared__ unsigned short T[64][72];
  const int b = blockIdx.z, c0 = blockIdx.x * 64, n0 = blockIdx.y * 64;
  const int t = threadIdx.x, nl = t & 63, w = t >> 6;
  const unsigned short* Sp = (const unsigned short*)S;
#pragma unroll
  for (int ci = 0; ci < 16; ++ci) {
    int cl = ci * 4 + w;
    T[nl][cl] = Sp[((size_t)(b * 512 + c0 + cl)) * 1600 + n0 + nl];
  }
  __syncthreads();
  const int n2 = t >> 2, cg = (t & 3) * 16;
  unsigned short* o = (unsigned short*)D + ((size_t)(b * 1600 + n0 + n2)) * 512 + c0 + cg;
  *(u16x8*)&o[0] = *(const u16x8*)&T[n2][cg];
  *(u16x8*)&o[8] = *(const u16x8*)&T[n2][cg + 8];
}

// ---------------------------------------------------------------------------
// QKV GEMM v6: m97 structure; q pre-scaled by QSCALE for exp2 domain.
// V outputs:
//   vb[b][c][n]  -> direct stores (32B runs), as in the round-0 baseline.
//   vp[bh][kb][d][8] -> staged in LDS Vs[128 n][68 d] then written
//     cooperatively as 1024 consecutive 16B chunks (fully coalesced 1KB
//     runs).
// ---------------------------------------------------------------------------
__global__ __launch_bounds__(256) void qkv_mfma_kernel(
    const short* __restrict__ XT, const short* __restrict__ WQ,
    const float* __restrict__ gamma, const float* __restrict__ beta,
    const float* __restrict__ mean, const float* __restrict__ var,
    short* __restrict__ qT, short* __restrict__ kT,
    short* __restrict__ vb, short* __restrict__ vp) {
  __shared__ __align__(16) unsigned short As[128 * 32];
  __shared__ __align__(16) unsigned short Bs[128 * 32];
  __shared__ __align__(16) unsigned short Vs[128 * 68];   // [n_local][d], pad 68

  const int t = threadIdx.x, w = t >> 6, lane = t & 63;
  const int quad = lane >> 4, l16 = lane & 15;
  const int wr = w >> 1, wc = w & 1;
  const int ngt = blockIdx.x, h = blockIdx.y;
  const int o0 = h * 128, ng0 = ngt * 128;

  const int srow = lane >> 2;
  const int sseg = (lane & 3) * 8;

  f32x4 acc[4][4];
#pragma unroll
  for (int mi = 0; mi < 4; ++mi)
#pragma unroll
    for (int nj = 0; nj < 4; ++nj) { acc[mi][nj][0]=0.f; acc[mi][nj][1]=0.f; acc[mi][nj][2]=0.f; acc[mi][nj][3]=0.f; }

  for (int kt = 0; kt < 16; ++kt) {
    const int c0 = kt * 32;
    if (kt) __syncthreads();
#pragma unroll
    for (int r = 0; r < 2; ++r) {
      const int row = (r * 4 + w) * 16 + srow;
      gload_lds16(WQ + (size_t)(o0 + row) * 512 + c0 + sseg, As + (r * 4 + w) * 512);
      gload_lds16(XT + (size_t)(ng0 + row) * 512 + c0 + sseg, Bs + (r * 4 + w) * 512);
    }
    __syncthreads();
    bf16x8 af[4], bfr[4];
#pragma unroll
    for (int i = 0; i < 4; ++i) {
      af[i]  = *(const bf16x8*)&As[(wr * 64 + i * 16 + l16) * 32 + quad * 8];
      bfr[i] = *(const bf16x8*)&Bs[(wc * 64 + i * 16 + l16) * 32 + quad * 8];
    }
#pragma unroll
    for (int mi = 0; mi < 4; ++mi)
#pragma unroll
      for (int nj = 0; nj < 4; ++nj)
        acc[mi][nj] = __builtin_amdgcn_mfma_f32_16x16x32_bf16(af[mi], bfr[nj], acc[mi][nj], 0, 0, 0);
  }

  const int ng_base = ng0 + wc * 64;
#pragma unroll
  for (int mi = 0; mi < 4; ++mi) {
    const int ol = wr * 64 + mi * 16 + quad * 4;
    const int ob = o0 + ol;
    float inv[4], add[4];
#pragma unroll
    for (int r = 0; r < 4; ++r) {
      inv[r] = gamma[ob + r] * rsqrtf(var[ob + r] + EPS);
      add[r] = beta[ob + r] - mean[ob + r] * inv[r];
    }
    const int region = wr * 2 + (mi >> 1);   // 0=q, 1=k, 2/3=v
    if (region == 0) {
      const int kk = mi * 16 + quad * 4;
#pragma unroll
      for (int nj = 0; nj < 4; ++nj) {
        int ng = ng_base + nj * 16 + l16;
        int b = ng / 1600, n = ng - b * 1600;
        ushort4 u;
        u.x = f2bf((acc[mi][nj][0] * inv[0] + add[0]) * QSCALE);
        u.y = f2bf((acc[mi][nj][1] * inv[1] + add[1]) * QSCALE);
        u.z = f2bf((acc[mi][nj][2] * inv[2] + add[2]) * QSCALE);
        u.w = f2bf((acc[mi][nj][3] * inv[3] + add[3]) * QSCALE);
        *(ushort4*)&qT[((size_t)(b * 8 + h) * 1600 + n) * 32 + kk] = u;
      }
    } else if (region == 1) {
      const int kk = (mi - 2) * 16 + quad * 4;
#pragma unroll
      for (int nj = 0; nj < 4; ++nj) {
        int ng = ng_base + nj * 16 + l16;
        int b = ng / 1600, n = ng - b * 1600;
        ushort4 u;
        u.x = f2bf(acc[mi][nj][0] * inv[0] + add[0]);
        u.y = f2bf(acc[mi][nj][1] * inv[1] + add[1]);
        u.z = f2bf(acc[mi][nj][2] * inv[2] + add[2]);
        u.w = f2bf(acc[mi][nj][3] * inv[3] + add[3]);
        *(ushort4*)&kT[((size_t)(b * 8 + h) * 1600 + n) * 32 + kk] = u;
      }
    } else {
      const int ch = h * 64 + (ol - 64);    // global channel (for vb)
      const int d0 = ol - 64;               // d within head: mi*16+quad*4
#pragma unroll
      for (int nj = 0; nj < 4; ++nj) {
        int ng = ng_base + nj * 16 + l16;
        int n_local = ng - ng0;             // wc*64 + nj*16 + l16
        int b = ng / 1600, n = ng - b * 1600;
        unsigned short val[4];
#pragma unroll
        for (int r = 0; r < 4; ++r)
          val[r] = f2bf(acc[mi][nj][r] * inv[r] + add[r]);
        // vb direct (baseline path, 32B runs)
#pragma unroll
        for (int r = 0; r < 4; ++r)
          ((unsigned short*)vb)[((size_t)(b * 512 + ch + r)) * 1600 + n] = val[r];
        // LDS stage for the coalesced vp write (ushort2 pairs, 4B aligned)
#pragma unroll
        for (int k = 0; k < 2; ++k) {
          unsigned int pk = (unsigned int)val[2 * k] |
                            ((unsigned int)val[2 * k + 1] << 16);
          *(unsigned int*)&Vs[n_local * 68 + d0 + 2 * k] = pk;
        }
      }
    }
  }

  __syncthreads();
  // Cooperative vp write: 1024 chunks (16 kb x 64 d); thread t emits 4.
#pragma unroll
  for (int cc = 0; cc < 4; ++cc) {
    const int c = cc * 256 + t;
    const int kbl = c >> 6, d = c & 63;
    const int n_gl = ng0 + kbl * 8;
    const int b = n_gl / 1600, nn = n_gl - b * 1600;
    union { unsigned short u[8]; u16x8 v; } pk;
#pragma unroll
    for (int j = 0; j < 8; ++j)
      pk.u[j] = Vs[(kbl * 8 + j) * 68 + d];
    *(u16x8*)((unsigned short*)vp +
        ((size_t)(b * 8 + h) * 200 + (nn >> 3)) * 512 + d * 8) = pk.v;
  }
}

// ---------------------------------------------------------------------------
// MFMA flash attention v11 (best measured: 63.0us): 32 q/wave, zero LDS /
// zero barriers, K-row-permuted QK^T A-operand, V' single-16B B-fragments,
// VALU den, static 1-tile-ahead register prefetch.
// ---------------------------------------------------------------------------
__global__ __launch_bounds__(256) void attn_mfma_kernel(
    const short* __restrict__ qT, const short* __restrict__ kT,
    const short* __restrict__ vp, short* __restrict__ ybf) {
  const int N = 1600;
  const int t = threadIdx.x;
  const int w = t >> 6, lane = t & 63, quad = lane >> 4, l16 = lane & 15;
  const int bh = blockIdx.x, b = bh >> 3, h = bh & 7;
  const int n0w = blockIdx.y * 128 + w * 32;   // this wave's 32 queries
  if (n0w >= 1600) return;                     // tail waves (no barriers -> ok)

  const unsigned short* qTb = (const unsigned short*)qT + (size_t)bh * N * 32;
  const unsigned short* kTb = (const unsigned short*)kT + (size_t)bh * N * 32;
  const unsigned short* vpb = (const unsigned short*)vp + (size_t)bh * 102400;

  // B-fragments of Q: col=l16 -> query, k=quad*8+j (full KEY_DIM=32)
  const bf16x8 qf0 = *(const bf16x8*)(qTb + (size_t)(n0w + l16) * 32 + quad * 8);
  const bf16x8 qf1 = *(const bf16x8*)(qTb + (size_t)(n0w + 16 + l16) * 32 + quad * 8);

  f32x4 acc0[4], acc1[4];
#pragma unroll
  for (int i = 0; i < 4; ++i) {
    acc0[i][0]=0.f; acc0[i][1]=0.f; acc0[i][2]=0.f; acc0[i][3]=0.f;
    acc1[i][0]=0.f; acc1[i][1]=0.f; acc1[i][2]=0.f; acc1[i][3]=0.f;
  }
  float den0 = 0.f, den1 = 0.f;
  const f32x4 zero4 = {0.f, 0.f, 0.f, 0.f};

  // K A-fragment row permutation: row l16 -> key 2*(l16&~3)+(l16&3)
  const int kperm = ((l16 & 12) << 1) + (l16 & 3);
  const unsigned short* kp = kTb + (size_t)kperm * 32 + quad * 8;
  // V' fragment base: lane (q,l16) reads keys (mt*4+q)*8..+7 at d=i*16+l16
  const unsigned short* vq = vpb + (size_t)quad * 512 + l16 * 8;

  // Prologue: tile 0 into the "c" buffer set.
  bf16x8 ck0 = *(const bf16x8*)kp;
  bf16x8 ck1 = *(const bf16x8*)(kp + 128);
  bf16x8 cv0 = *(const bf16x8*)(vq);
  bf16x8 cv1 = *(const bf16x8*)(vq + 128);
  bf16x8 cv2 = *(const bf16x8*)(vq + 256);
  bf16x8 cv3 = *(const bf16x8*)(vq + 384);
  bf16x8 nk0, nk1, nv0, nv1, nv2, nv3;

  // Body: prefetch tile NXT into the N-set, compute the C-set's tile.
#define ATTN_BODY(NXT, CK0, CK1, CV0, CV1, CV2, CV3, NK0, NK1, NV0, NV1, NV2, NV3) \
  { \
    const int nx_ = (NXT) < 50 ? (NXT) : 0; \
    const unsigned short* kpn_ = kp + (size_t)nx_ * 1024; \
    const unsigned short* vqn_ = vq + (size_t)nx_ * 2048; \
    NK0 = *(const bf16x8*)kpn_; \
    NK1 = *(const bf16x8*)(kpn_ + 128); \
    NV0 = *(const bf16x8*)(vqn_); \
    NV1 = *(const bf16x8*)(vqn_ + 128); \
    NV2 = *(const bf16x8*)(vqn_ + 256); \
    NV3 = *(const bf16x8*)(vqn_ + 384); \
    f32x4 s0_ = __builtin_amdgcn_mfma_f32_16x16x32_bf16(CK0, qf0, zero4, 0, 0, 0); \
    f32x4 s1_ = __builtin_amdgcn_mfma_f32_16x16x32_bf16(CK1, qf0, zero4, 0, 0, 0); \
    f32x4 t0_ = __builtin_amdgcn_mfma_f32_16x16x32_bf16(CK0, qf1, zero4, 0, 0, 0); \
    f32x4 t1_ = __builtin_amdgcn_mfma_f32_16x16x32_bf16(CK1, qf1, zero4, 0, 0, 0); \
    float a0_ = fexp2(s0_[0]), a1_ = fexp2(s0_[1]), a2_ = fexp2(s0_[2]), a3_ = fexp2(s0_[3]); \
    float a4_ = fexp2(s1_[0]), a5_ = fexp2(s1_[1]), a6_ = fexp2(s1_[2]), a7_ = fexp2(s1_[3]); \
    float b0_ = fexp2(t0_[0]), b1_ = fexp2(t0_[1]), b2_ = fexp2(t0_[2]), b3_ = fexp2(t0_[3]); \
    float b4_ = fexp2(t1_[0]), b5_ = fexp2(t1_[1]), b6_ = fexp2(t1_[2]), b7_ = fexp2(t1_[3]); \
    den0 += ((a0_ + a1_) + (a2_ + a3_)) + ((a4_ + a5_) + (a6_ + a7_)); \
    den1 += ((b0_ + b1_) + (b2_ + b3_)) + ((b4_ + b5_) + (b6_ + b7_)); \
    union { bf16x8 v; uint4 u; } pk0_, pk1_; \
    pk0_.u.x = pack_bf_trunc(a0_, a1_); pk0_.u.y = pack_bf_trunc(a2_, a3_); \
    pk0_.u.z = pack_bf_trunc(a4_, a5_); pk0_.u.w = pack_bf_trunc(a6_, a7_); \
    pk1_.u.x = pack_bf_trunc(b0_, b1_); pk1_.u.y = pack_bf_trunc(b2_, b3_); \
    pk1_.u.z = pack_bf_trunc(b4_, b5_); pk1_.u.w = pack_bf_trunc(b6_, b7_); \
    acc0[0] = __builtin_amdgcn_mfma_f32_16x16x32_bf16(pk0_.v, CV0, acc0[0], 0, 0, 0); \
    acc1[0] = __builtin_amdgcn_mfma_f32_16x16x32_bf16(pk1_.v, CV0, acc1[0], 0, 0, 0); \
    acc0[1] = __builtin_amdgcn_mfma_f32_16x16x32_bf16(pk0_.v, CV1, acc0[1], 0, 0, 0); \
    acc1[1] = __builtin_amdgcn_mfma_f32_16x16x32_bf16(pk1_.v, CV1, acc1[1], 0, 0, 0); \
    acc0[2] = __builtin_amdgcn_mfma_f32_16x16x32_bf16(pk0_.v, CV2, acc0[2], 0, 0, 0); \
    acc1[2] = __builtin_amdgcn_mfma_f32_16x16x32_bf16(pk1_.v, CV2, acc1[2], 0, 0, 0); \
    acc0[3] = __builtin_amdgcn_mfma_f32_16x16x32_bf16(pk0_.v, CV3, acc0[3], 0, 0, 0); \
    acc1[3] = __builtin_amdgcn_mfma_f32_16x16x32_bf16(pk1_.v, CV3, acc1[3], 0, 0, 0); \
  }

#pragma unroll 1
  for (int mt2 = 0; mt2 < 25; ++mt2) {
    ATTN_BODY(2 * mt2 + 1, ck0, ck1, cv0, cv1, cv2, cv3, nk0, nk1, nv0, nv1, nv2, nv3);
    ATTN_BODY(2 * mt2 + 2, nk0, nk1, nv0, nv1, nv2, nv3, ck0, ck1, cv0, cv1, cv2, cv3);
  }
#undef ATTN_BODY

  // den(lane q,l16) covers keys of quad q only -> reduce across quads
  den0 += __shfl_xor(den0, 16, 64);
  den0 += __shfl_xor(den0, 32, 64);
  den1 += __shfl_xor(den1, 16, 64);
  den1 += __shfl_xor(den1, 32, 64);
  const float rden0 = 1.f / den0;   // for query n0w + l16
  const float rden1 = 1.f / den1;   // for query n0w + 16 + l16
  // acc rows are queries quad*4+r -> fetch their rden from lanes 0..15
  float dv0[4], dv1[4];
#pragma unroll
  for (int r = 0; r < 4; ++r) {
    dv0[r] = __shfl(rden0, quad * 4 + r, 64);
    dv1[r] = __shfl(rden1, quad * 4 + r, 64);
  }

  unsigned short* yb = (unsigned short*)ybf + ((size_t)b * 512 + h * 64) * N;
#pragma unroll
  for (int i = 0; i < 4; ++i) {
    const size_t rowo = (size_t)(i * 16 + l16) * N;
    ushort4 o4;
    o4.x = f2bf(acc0[i][0] * dv0[0]);
    o4.y = f2bf(acc0[i][1] * dv0[1]);
    o4.z = f2bf(acc0[i][2] * dv0[2]);
    o4.w = f2bf(acc0[i][3] * dv0[3]);
    *(ushort4*)&yb[rowo + n0w + quad * 4] = o4;
    o4.x = f2bf(acc1[i][0] * dv1[0]);
    o4.y = f2bf(acc1[i][1] * dv1[1]);
    o4.z = f2bf(acc1[i][2] * dv1[2]);
    o4.w = f2bf(acc1[i][3] * dv1[3]);
    *(ushort4*)&yb[rowo + n0w + 16 + quad * 4] = o4;
  }
}

// ---------------------------------------------------------------------------
// PE v5: vectorized 8-wide. Each thread computes 8 row-contiguous outputs:
// per dy-row one aligned u16x8 LDS load + 2 scalar edge loads (was 72 scalar
// ds_read_u16 per 8 outputs), and 16B global Ybf-read / YB-write (was
// scalar ushort). Conv FMA count unchanged; instruction issue count ~7x lower.
// ---------------------------------------------------------------------------
__global__ __launch_bounds__(256) void pe_kernel(
    const short* __restrict__ Ybf, const short* __restrict__ VB,
    const float* __restrict__ pw,
    const float* __restrict__ gamma, const float* __restrict__ beta,
    const float* __restrict__ mean, const float* __restrict__ var,
    short* __restrict__ YB) {
  __shared__ __align__(16) unsigned short V[4 * 42 * 56];
  __shared__ float wlds[36];
  __shared__ float invs[4], adds[4];

  const int t = threadIdx.x;
  const int b = blockIdx.y, c0 = blockIdx.x * 4;

  const u16x8 z = {0, 0, 0, 0, 0, 0, 0, 0};
  for (int k = t; k < 1176; k += 256)
    *(u16x8*)&V[k * 8] = z;
  if (t < 36) wlds[t] = pw[c0 * 9 + t];
  if (t < 4) {
    int c = c0 + t;
    float inv = gamma[c] * rsqrtf(var[c] + EPS);
    invs[t] = inv;
    adds[t] = beta[c] - mean[c] * inv;
  }
  __syncthreads();

  for (int u = t; u < 800; u += 256) {
    int ch = u / 200, j = u - ch * 200;
    int row = j / 5, col8 = (j - row * 5) * 8;
    u16x8 d = *(const u16x8*)((const unsigned short*)VB +
        ((size_t)(b * 512 + c0 + ch) * 1600 + row * 40 + col8));
    *(u16x8*)&V[ch * 2352 + (row + 1) * 56 + 8 + col8] = d;
  }
  __syncthreads();

  for (int u = t; u < 800; u += 256) {
    int ch = u / 200, j = u - ch * 200;
    int row = j / 5, col8 = (j - row * 5) * 8;
    const unsigned short* Vc = &V[ch * 2352 + (row + 1) * 56 + 8 + col8];
    const float* wk = &wlds[ch * 9];
    float s[8];
#pragma unroll
    for (int jj = 0; jj < 8; ++jj) s[jj] = 0.f;
#pragma unroll
    for (int dy = 0; dy < 3; ++dy) {
      const unsigned short* Vr = Vc + (dy - 1) * 56;
      u16x8 cv = *(const u16x8*)Vr;           // aligned (pad-8 + 56-col row)
      float c[8];
#pragma unroll
      for (int jj = 0; jj < 8; ++jj) c[jj] = bf2f(cv[jj]);
      float left = bf2f(Vr[-1]);
      float right = bf2f(Vr[8]);
      const float w0 = wk[dy * 3 + 0], w1 = wk[dy * 3 + 1], w2 = wk[dy * 3 + 2];
      s[0] += w0 * left + w1 * c[0] + w2 * c[1];
#pragma unroll
      for (int jj = 1; jj < 7; ++jj)
        s[jj] += w0 * c[jj - 1] + w1 * c[jj] + w2 * c[jj + 1];
      s[7] += w0 * c[6] + w1 * c[7] + w2 * right;
    }
    size_t idx = (size_t)(b * 512 + c0 + ch) * 1600 + row * 40 + col8;
    u16x8 yv = *(const u16x8*)((const unsigned short*)Ybf + idx);
    union { unsigned short u[8]; u16x8 v; } o;
#pragma unroll
    for (int jj = 0; jj < 8; ++jj)
      o.u[jj] = f2bf(bf2f(yv[jj]) + s[jj] * invs[ch] + adds[ch]);
    *(u16x8*)((unsigned short*)YB + idx) = o.v;
  }
}

// ---------------------------------------------------------------------------
// Proj GEMM v3 (m97 structure, unchanged).
// ---------------------------------------------------------------------------
__global__ __launch_bounds__(256) void proj_mfma_kernel(
    const short* __restrict__ YT, const short* __restrict__ WP,
    const float* __restrict__ gamma, const float* __restrict__ beta,
    const float* __restrict__ mean, const float* __restrict__ var,
    float* __restrict__ OUT) {
  __shared__ __align__(16) unsigned short As[64 * 32];
  __shared__ __align__(16) unsigned short Bs[128 * 32];

  const int t = threadIdx.x, w = t >> 6, lane = t & 63;
  const int quad = lane >> 4, l16 = lane & 15;
  const int wr = w >> 1, wc = w & 1;
  const int ngt = blockIdx.x;
  const int o0 = blockIdx.y * 64;
  const int ng0 = ngt * 128;

  const int srow = lane >> 2;
  const int sseg = (lane & 3) * 8;

  f32x4 acc[2][4];
#pragma unroll
  for (int mi = 0; mi < 2; ++mi)
#pragma unroll
    for (int nj = 0; nj < 4; ++nj) { acc[mi][nj][0]=0.f; acc[mi][nj][1]=0.f; acc[mi][nj][2]=0.f; acc[mi][nj][3]=0.f; }

  for (int kt = 0; kt < 16; ++kt) {
    const int c0 = kt * 32;
    if (kt) __syncthreads();
    {
      const int row = w * 16 + srow;
      gload_lds16(WP + (size_t)(o0 + row) * 512 + c0 + sseg, As + w * 512);
    }
#pragma unroll
    for (int r = 0; r < 2; ++r) {
      const int row = (r * 4 + w) * 16 + srow;
      gload_lds16(YT + (size_t)(ng0 + row) * 512 + c0 + sseg, Bs + (r * 4 + w) * 512);
    }
    __syncthreads();
    bf16x8 af[2], bfr[4];
#pragma unroll
    for (int i = 0; i < 2; ++i)
      af[i] = *(const bf16x8*)&As[(wr * 32 + i * 16 + l16) * 32 + quad * 8];
#pragma unroll
    for (int i = 0; i < 4; ++i)
      bfr[i] = *(const bf16x8*)&Bs[(wc * 64 + i * 16 + l16) * 32 + quad * 8];
#pragma unroll
    for (int mi = 0; mi < 2; ++mi)
#pragma unroll
      for (int nj = 0; nj < 4; ++nj)
        acc[mi][nj] = __builtin_amdgcn_mfma_f32_16x16x32_bf16(af[mi], bfr[nj], acc[mi][nj], 0, 0, 0);
  }

  const int ng_base = ng0 + wc * 64;
#pragma unroll
  for (int mi = 0; mi < 2; ++mi) {
    const int ob = o0 + wr * 32 + mi * 16 + quad * 4;
    float inv[4], add[4];
#pragma unroll
    for (int r = 0; r < 4; ++r) {
      inv[r] = gamma[ob + r] * rsqrtf(var[ob + r] + EPS);
      add[r] = beta[ob + r] - mean[ob + r] * inv[r];
    }
#pragma unroll
    for (int nj = 0; nj < 4; ++nj) {
      int ng = ng_base + nj * 16 + l16;
      int b = ng / 1600, n = ng - b * 1600;
#pragma unroll
      for (int r = 0; r < 4; ++r)
        OUT[((size_t)(b * 512 + ob + r)) * 1600 + n] = acc[mi][nj][r] * inv[r] + add[r];
    }
  }
}

// ---------------------------------------------------------------------------
extern "C" void kernel_launch(void* const* d_in, const int* in_sizes, int n_in,
                              void* d_out, int out_size, void* d_ws, size_t ws_size,
                              hipStream_t stream) {
  const float* x          = (const float*)d_in[0];
  const float* qkv_w      = (const float*)d_in[1];
  const float* qkv_gamma  = (const float*)d_in[2];
  const float* qkv_beta   = (const float*)d_in[3];
  const float* qkv_mean   = (const float*)d_in[4];
  const float* qkv_var    = (const float*)d_in[5];
  const float* pe_w       = (const float*)d_in[6];
  const float* pe_gamma   = (const float*)d_in[7];
  const float* pe_beta    = (const float*)d_in[8];
  const float* pe_mean    = (const float*)d_in[9];
  const float* pe_var     = (const float*)d_in[10];
  const float* proj_w     = (const float*)d_in[11];
  const float* proj_gamma = (const float*)d_in[12];
  const float* proj_beta  = (const float*)d_in[13];
  const float* proj_mean  = (const float*)d_in[14];
  const float* proj_var   = (const float*)d_in[15];
  float* out = (float*)d_out;

  float* ws_a = (float*)d_ws;
  short* ybf_attn = (short*)d_ws;                 // 6.55M shorts used
  short* vp   = ybf_attn + (size_t)6553600;       // dead half of 26.2MB region
  short* qT   = (short*)(ws_a + (size_t)6553600);
  short* kT   = qT + (size_t)3276800;
  short* vb   = kT + (size_t)3276800;
  short* xT   = vb + (size_t)6553600;
  short* wq   = xT + (size_t)6553600;
  short* wp   = wq + (size_t)524288;
  short* yT   = xT;
  short* ybf_pe = qT;

  cast_w_kernel<<<768, 256, 0, stream>>>(qkv_w, proj_w, wq, wp);
  {
    dim3 grid(8, 25, 8), block(256);
    transpose_cast_kernel<<<grid, block, 0, stream>>>(x, xT);
  }
  {
    dim3 grid(100, 8), block(256);
    qkv_mfma_kernel<<<grid, block, 0, stream>>>(
        xT, wq, qkv_gamma, qkv_beta, qkv_mean, qkv_var, qT, kT, vb, vp);
  }
  {
    dim3 grid(64, 13), block(256);
    attn_mfma_kernel<<<grid, block, 0, stream>>>(qT, kT, vp, ybf_attn);
  }
  {
    dim3 grid(128, 8), block(256);
    pe_kernel<<<grid, block, 0, stream>>>(
        ybf_attn, vb, pe_w, pe_gamma, pe_beta, pe_mean, pe_var, ybf_pe);
  }
  {
    dim3 grid(8, 25, 8), block(256);
    transpose16_kernel<<<grid, block, 0, stream>>>(ybf_pe, yT);
  }
  {
    dim3 grid(100, 8), block(256);
    proj_mfma_kernel<<<grid, block, 0, stream>>>(
        yT, wp, proj_gamma, proj_beta, proj_mean, proj_var, out);
  }
}

// Round 12
// 221.988 us; speedup vs baseline: 1.0684x; 1.0185x over previous
//
#include <hip/hip_runtime.h>
#include <hip/hip_bf16.h>

#define EPS 1e-5f
#define SCALE 0.17677669529663687f    // 32^-0.5
#define QSCALE 0.25500526817095634f   // SCALE * log2(e): attn uses exp2

typedef __attribute__((ext_vector_type(8))) short bf16x8;
typedef __attribute__((ext_vector_type(4))) float f32x4;
typedef __attribute__((ext_vector_type(8))) unsigned short u16x8;

__device__ __forceinline__ unsigned short f2bf(float x) {
  union { float f; unsigned int u; } a; a.f = x;
  unsigned int r = a.u + 0x7FFFu + ((a.u >> 16) & 1u);
  return (unsigned short)(r >> 16);
}
__device__ __forceinline__ float bf2f(unsigned short u) {
  union { unsigned int u; float f; } a; a.u = ((unsigned int)u) << 16;
  return a.f;
}

// single-instruction v_exp_f32 (2^x).
__device__ __forceinline__ float fexp2(float x) {
#if __has_builtin(__builtin_amdgcn_exp2f)
  return __builtin_amdgcn_exp2f(x);
#else
  float r; asm("v_exp_f32 %0, %1" : "=v"(r) : "v"(x)); return r;
#endif
}

// async global->LDS, 16 B per lane; lds base wave-uniform, HW writes lane i
// at ldsbase + i*16 (guide §5 / m97).
__device__ __forceinline__ void gload_lds16(const void* g, void* l) {
  __builtin_amdgcn_global_load_lds(
      (const __attribute__((address_space(1))) unsigned int*)g,
      (__attribute__((address_space(3))) unsigned int*)l, 16, 0, 0);
}

// pack high halves of two f32 -> [hi16(b) : hi16(a)] (truncation, 1 v_perm)
__device__ __forceinline__ unsigned int pack_bf_trunc(float a, float b) {
  return __builtin_amdgcn_perm(__float_as_uint(b), __float_as_uint(a), 0x07060302u);
}

// ---------------------------------------------------------------------------
// Cast qkv_w (1024x512) and proj_w (512x512) fp32 -> bf16, same layout.
// ---------------------------------------------------------------------------
__global__ __launch_bounds__(256) void cast_w_kernel(
    const float* __restrict__ qw, const float* __restrict__ pw,
    short* __restrict__ wq, short* __restrict__ wp) {
  int idx = blockIdx.x * 256 + threadIdx.x;
  const float4* src;
  ushort4* dst;
  if (idx < 131072) {
    src = (const float4*)qw + idx;
    dst = (ushort4*)wq + idx;
  } else {
    src = (const float4*)pw + (idx - 131072);
    dst = (ushort4*)wp + (idx - 131072);
  }
  float4 v = *src;
  ushort4 u;
  u.x = f2bf(v.x); u.y = f2bf(v.y); u.z = f2bf(v.z); u.w = f2bf(v.w);
  *dst = u;
}

// ---------------------------------------------------------------------------
// Transpose-cast X (B,512,1600) fp32 -> XT (B,1600,512) bf16. 64x64 LDS tile.
// ---------------------------------------------------------------------------
__global__ __launch_bounds__(256) void transpose_cast_kernel(
    const float* __restrict__ X, short* __restrict__ XT) {
  __shared__ unsigned short T[64][72];
  const int b = blockIdx.z, c0 = blockIdx.x * 64, n0 = blockIdx.y * 64;
  const int t = threadIdx.x, nl = t & 63, w = t >> 6;
#pragma unroll
  for (int ci = 0; ci < 16; ++ci) {
    int cl = ci * 4 + w;
    T[nl][cl] = f2bf(X[((size_t)(b * 512 + c0 + cl)) * 1600 + n0 + nl]);
  }
  __syncthreads();
  const int n2 = t >> 2, cg = (t & 3) * 16;
  unsigned short* o = (unsigned short*)XT + ((size_t)(b * 1600 + n0 + n2)) * 512 + c0 + cg;
  *(u16x8*)&o[0] = *(const u16x8*)&T[n2][cg];
  *(u16x8*)&o[8] = *(const u16x8*)&T[n2][cg + 8];
}

// ---------------------------------------------------------------------------
// QKV GEMM v7: m97 structure; q pre-scaled by QSCALE for exp2 domain.
// V output: ONLY vp[bh][kb][d][8] (LDS-staged, coalesced 1KB runs).
// vb dropped entirely (pe now reads vp).
// ---------------------------------------------------------------------------
__global__ __launch_bounds__(256) void qkv_mfma_kernel(
    const short* __restrict__ XT, const short* __restrict__ WQ,
    const float* __restrict__ gamma, const float* __restrict__ beta,
    const float* __restrict__ mean, const float* __restrict__ var,
    short* __restrict__ qT, short* __restrict__ kT, short* __restrict__ vp) {
  __shared__ __align__(16) unsigned short As[128 * 32];
  __shared__ __align__(16) unsigned short Bs[128 * 32];
  __shared__ __align__(16) unsigned short Vs[128 * 68];   // [n_local][d], pad 68

  const int t = threadIdx.x, w = t >> 6, lane = t & 63;
  const int quad = lane >> 4, l16 = lane & 15;
  const int wr = w >> 1, wc = w & 1;
  const int ngt = blockIdx.x, h = blockIdx.y;
  const int o0 = h * 128, ng0 = ngt * 128;

  const int srow = lane >> 2;
  const int sseg = (lane & 3) * 8;

  f32x4 acc[4][4];
#pragma unroll
  for (int mi = 0; mi < 4; ++mi)
#pragma unroll
    for (int nj = 0; nj < 4; ++nj) { acc[mi][nj][0]=0.f; acc[mi][nj][1]=0.f; acc[mi][nj][2]=0.f; acc[mi][nj][3]=0.f; }

  for (int kt = 0; kt < 16; ++kt) {
    const int c0 = kt * 32;
    if (kt) __syncthreads();
#pragma unroll
    for (int r = 0; r < 2; ++r) {
      const int row = (r * 4 + w) * 16 + srow;
      gload_lds16(WQ + (size_t)(o0 + row) * 512 + c0 + sseg, As + (r * 4 + w) * 512);
      gload_lds16(XT + (size_t)(ng0 + row) * 512 + c0 + sseg, Bs + (r * 4 + w) * 512);
    }
    __syncthreads();
    bf16x8 af[4], bfr[4];
#pragma unroll
    for (int i = 0; i < 4; ++i) {
      af[i]  = *(const bf16x8*)&As[(wr * 64 + i * 16 + l16) * 32 + quad * 8];
      bfr[i] = *(const bf16x8*)&Bs[(wc * 64 + i * 16 + l16) * 32 + quad * 8];
    }
#pragma unroll
    for (int mi = 0; mi < 4; ++mi)
#pragma unroll
      for (int nj = 0; nj < 4; ++nj)
        acc[mi][nj] = __builtin_amdgcn_mfma_f32_16x16x32_bf16(af[mi], bfr[nj], acc[mi][nj], 0, 0, 0);
  }

  const int ng_base = ng0 + wc * 64;
#pragma unroll
  for (int mi = 0; mi < 4; ++mi) {
    const int ol = wr * 64 + mi * 16 + quad * 4;
    const int ob = o0 + ol;
    float inv[4], add[4];
#pragma unroll
    for (int r = 0; r < 4; ++r) {
      inv[r] = gamma[ob + r] * rsqrtf(var[ob + r] + EPS);
      add[r] = beta[ob + r] - mean[ob + r] * inv[r];
    }
    const int region = wr * 2 + (mi >> 1);   // 0=q, 1=k, 2/3=v
    if (region == 0) {
      const int kk = mi * 16 + quad * 4;
#pragma unroll
      for (int nj = 0; nj < 4; ++nj) {
        int ng = ng_base + nj * 16 + l16;
        int b = ng / 1600, n = ng - b * 1600;
        ushort4 u;
        u.x = f2bf((acc[mi][nj][0] * inv[0] + add[0]) * QSCALE);
        u.y = f2bf((acc[mi][nj][1] * inv[1] + add[1]) * QSCALE);
        u.z = f2bf((acc[mi][nj][2] * inv[2] + add[2]) * QSCALE);
        u.w = f2bf((acc[mi][nj][3] * inv[3] + add[3]) * QSCALE);
        *(ushort4*)&qT[((size_t)(b * 8 + h) * 1600 + n) * 32 + kk] = u;
      }
    } else if (region == 1) {
      const int kk = (mi - 2) * 16 + quad * 4;
#pragma unroll
      for (int nj = 0; nj < 4; ++nj) {
        int ng = ng_base + nj * 16 + l16;
        int b = ng / 1600, n = ng - b * 1600;
        ushort4 u;
        u.x = f2bf(acc[mi][nj][0] * inv[0] + add[0]);
        u.y = f2bf(acc[mi][nj][1] * inv[1] + add[1]);
        u.z = f2bf(acc[mi][nj][2] * inv[2] + add[2]);
        u.w = f2bf(acc[mi][nj][3] * inv[3] + add[3]);
        *(ushort4*)&kT[((size_t)(b * 8 + h) * 1600 + n) * 32 + kk] = u;
      }
    } else {
      const int d0 = ol - 64;               // d within head: (mi-2)*16+quad*4
#pragma unroll
      for (int nj = 0; nj < 4; ++nj) {
        int ng = ng_base + nj * 16 + l16;
        int n_local = ng - ng0;             // wc*64 + nj*16 + l16
        unsigned short val[4];
#pragma unroll
        for (int r = 0; r < 4; ++r)
          val[r] = f2bf(acc[mi][nj][r] * inv[r] + add[r]);
        // LDS stage for the coalesced vp write (ushort2 pairs, 4B aligned)
#pragma unroll
        for (int k = 0; k < 2; ++k) {
          unsigned int pk = (unsigned int)val[2 * k] |
                            ((unsigned int)val[2 * k + 1] << 16);
          *(unsigned int*)&Vs[n_local * 68 + d0 + 2 * k] = pk;
        }
      }
    }
  }

  __syncthreads();
  // Cooperative vp write: 1024 chunks (16 kb x 64 d); thread t emits 4.
#pragma unroll
  for (int cc = 0; cc < 4; ++cc) {
    const int c = cc * 256 + t;
    const int kbl = c >> 6, d = c & 63;
    const int n_gl = ng0 + kbl * 8;
    const int b = n_gl / 1600, nn = n_gl - b * 1600;
    union { unsigned short u[8]; u16x8 v; } pk;
#pragma unroll
    for (int j = 0; j < 8; ++j)
      pk.u[j] = Vs[(kbl * 8 + j) * 68 + d];
    *(u16x8*)((unsigned short*)vp +
        ((size_t)(b * 8 + h) * 200 + (nn >> 3)) * 512 + d * 8) = pk.v;
  }
}

// ---------------------------------------------------------------------------
// MFMA flash attention v11 (best measured): 32 q/wave, zero LDS / zero
// barriers, K-row-permuted QK^T A-operand, V' single-16B B-fragments,
// VALU den, static 1-tile-ahead register prefetch.
// ---------------------------------------------------------------------------
__global__ __launch_bounds__(256) void attn_mfma_kernel(
    const short* __restrict__ qT, const short* __restrict__ kT,
    const short* __restrict__ vp, short* __restrict__ ybf) {
  const int N = 1600;
  const int t = threadIdx.x;
  const int w = t >> 6, lane = t & 63, quad = lane >> 4, l16 = lane & 15;
  const int bh = blockIdx.x, b = bh >> 3, h = bh & 7;
  const int n0w = blockIdx.y * 128 + w * 32;   // this wave's 32 queries
  if (n0w >= 1600) return;                     // tail waves (no barriers -> ok)

  const unsigned short* qTb = (const unsigned short*)qT + (size_t)bh * N * 32;
  const unsigned short* kTb = (const unsigned short*)kT + (size_t)bh * N * 32;
  const unsigned short* vpb = (const unsigned short*)vp + (size_t)bh * 102400;

  // B-fragments of Q: col=l16 -> query, k=quad*8+j (full KEY_DIM=32)
  const bf16x8 qf0 = *(const bf16x8*)(qTb + (size_t)(n0w + l16) * 32 + quad * 8);
  const bf16x8 qf1 = *(const bf16x8*)(qTb + (size_t)(n0w + 16 + l16) * 32 + quad * 8);

  f32x4 acc0[4], acc1[4];
#pragma unroll
  for (int i = 0; i < 4; ++i) {
    acc0[i][0]=0.f; acc0[i][1]=0.f; acc0[i][2]=0.f; acc0[i][3]=0.f;
    acc1[i][0]=0.f; acc1[i][1]=0.f; acc1[i][2]=0.f; acc1[i][3]=0.f;
  }
  float den0 = 0.f, den1 = 0.f;
  const f32x4 zero4 = {0.f, 0.f, 0.f, 0.f};

  // K A-fragment row permutation: row l16 -> key 2*(l16&~3)+(l16&3)
  const int kperm = ((l16 & 12) << 1) + (l16 & 3);
  const unsigned short* kp = kTb + (size_t)kperm * 32 + quad * 8;
  // V' fragment base: lane (q,l16) reads keys (mt*4+q)*8..+7 at d=i*16+l16
  const unsigned short* vq = vpb + (size_t)quad * 512 + l16 * 8;

  // Prologue: tile 0 into the "c" buffer set.
  bf16x8 ck0 = *(const bf16x8*)kp;
  bf16x8 ck1 = *(const bf16x8*)(kp + 128);
  bf16x8 cv0 = *(const bf16x8*)(vq);
  bf16x8 cv1 = *(const bf16x8*)(vq + 128);
  bf16x8 cv2 = *(const bf16x8*)(vq + 256);
  bf16x8 cv3 = *(const bf16x8*)(vq + 384);
  bf16x8 nk0, nk1, nv0, nv1, nv2, nv3;

  // Body: prefetch tile NXT into the N-set, compute the C-set's tile.
#define ATTN_BODY(NXT, CK0, CK1, CV0, CV1, CV2, CV3, NK0, NK1, NV0, NV1, NV2, NV3) \
  { \
    const int nx_ = (NXT) < 50 ? (NXT) : 0; \
    const unsigned short* kpn_ = kp + (size_t)nx_ * 1024; \
    const unsigned short* vqn_ = vq + (size_t)nx_ * 2048; \
    NK0 = *(const bf16x8*)kpn_; \
    NK1 = *(const bf16x8*)(kpn_ + 128); \
    NV0 = *(const bf16x8*)(vqn_); \
    NV1 = *(const bf16x8*)(vqn_ + 128); \
    NV2 = *(const bf16x8*)(vqn_ + 256); \
    NV3 = *(const bf16x8*)(vqn_ + 384); \
    f32x4 s0_ = __builtin_amdgcn_mfma_f32_16x16x32_bf16(CK0, qf0, zero4, 0, 0, 0); \
    f32x4 s1_ = __builtin_amdgcn_mfma_f32_16x16x32_bf16(CK1, qf0, zero4, 0, 0, 0); \
    f32x4 t0_ = __builtin_amdgcn_mfma_f32_16x16x32_bf16(CK0, qf1, zero4, 0, 0, 0); \
    f32x4 t1_ = __builtin_amdgcn_mfma_f32_16x16x32_bf16(CK1, qf1, zero4, 0, 0, 0); \
    float a0_ = fexp2(s0_[0]), a1_ = fexp2(s0_[1]), a2_ = fexp2(s0_[2]), a3_ = fexp2(s0_[3]); \
    float a4_ = fexp2(s1_[0]), a5_ = fexp2(s1_[1]), a6_ = fexp2(s1_[2]), a7_ = fexp2(s1_[3]); \
    float b0_ = fexp2(t0_[0]), b1_ = fexp2(t0_[1]), b2_ = fexp2(t0_[2]), b3_ = fexp2(t0_[3]); \
    float b4_ = fexp2(t1_[0]), b5_ = fexp2(t1_[1]), b6_ = fexp2(t1_[2]), b7_ = fexp2(t1_[3]); \
    den0 += ((a0_ + a1_) + (a2_ + a3_)) + ((a4_ + a5_) + (a6_ + a7_)); \
    den1 += ((b0_ + b1_) + (b2_ + b3_)) + ((b4_ + b5_) + (b6_ + b7_)); \
    union { bf16x8 v; uint4 u; } pk0_, pk1_; \
    pk0_.u.x = pack_bf_trunc(a0_, a1_); pk0_.u.y = pack_bf_trunc(a2_, a3_); \
    pk0_.u.z = pack_bf_trunc(a4_, a5_); pk0_.u.w = pack_bf_trunc(a6_, a7_); \
    pk1_.u.x = pack_bf_trunc(b0_, b1_); pk1_.u.y = pack_bf_trunc(b2_, b3_); \
    pk1_.u.z = pack_bf_trunc(b4_, b5_); pk1_.u.w = pack_bf_trunc(b6_, b7_); \
    acc0[0] = __builtin_amdgcn_mfma_f32_16x16x32_bf16(pk0_.v, CV0, acc0[0], 0, 0, 0); \
    acc1[0] = __builtin_amdgcn_mfma_f32_16x16x32_bf16(pk1_.v, CV0, acc1[0], 0, 0, 0); \
    acc0[1] = __builtin_amdgcn_mfma_f32_16x16x32_bf16(pk0_.v, CV1, acc0[1], 0, 0, 0); \
    acc1[1] = __builtin_amdgcn_mfma_f32_16x16x32_bf16(pk1_.v, CV1, acc1[1], 0, 0, 0); \
    acc0[2] = __builtin_amdgcn_mfma_f32_16x16x32_bf16(pk0_.v, CV2, acc0[2], 0, 0, 0); \
    acc1[2] = __builtin_amdgcn_mfma_f32_16x16x32_bf16(pk1_.v, CV2, acc1[2], 0, 0, 0); \
    acc0[3] = __builtin_amdgcn_mfma_f32_16x16x32_bf16(pk0_.v, CV3, acc0[3], 0, 0, 0); \
    acc1[3] = __builtin_amdgcn_mfma_f32_16x16x32_bf16(pk1_.v, CV3, acc1[3], 0, 0, 0); \
  }

#pragma unroll 1
  for (int mt2 = 0; mt2 < 25; ++mt2) {
    ATTN_BODY(2 * mt2 + 1, ck0, ck1, cv0, cv1, cv2, cv3, nk0, nk1, nv0, nv1, nv2, nv3);
    ATTN_BODY(2 * mt2 + 2, nk0, nk1, nv0, nv1, nv2, nv3, ck0, ck1, cv0, cv1, cv2, cv3);
  }
#undef ATTN_BODY

  // den(lane q,l16) covers keys of quad q only -> reduce across quads
  den0 += __shfl_xor(den0, 16, 64);
  den0 += __shfl_xor(den0, 32, 64);
  den1 += __shfl_xor(den1, 16, 64);
  den1 += __shfl_xor(den1, 32, 64);
  const float rden0 = 1.f / den0;   // for query n0w + l16
  const float rden1 = 1.f / den1;   // for query n0w + 16 + l16
  // acc rows are queries quad*4+r -> fetch their rden from lanes 0..15
  float dv0[4], dv1[4];
#pragma unroll
  for (int r = 0; r < 4; ++r) {
    dv0[r] = __shfl(rden0, quad * 4 + r, 64);
    dv1[r] = __shfl(rden1, quad * 4 + r, 64);
  }

  unsigned short* yb = (unsigned short*)ybf + ((size_t)b * 512 + h * 64) * N;
#pragma unroll
  for (int i = 0; i < 4; ++i) {
    const size_t rowo = (size_t)(i * 16 + l16) * N;
    ushort4 o4;
    o4.x = f2bf(acc0[i][0] * dv0[0]);
    o4.y = f2bf(acc0[i][1] * dv0[1]);
    o4.z = f2bf(acc0[i][2] * dv0[2]);
    o4.w = f2bf(acc0[i][3] * dv0[3]);
    *(ushort4*)&yb[rowo + n0w + quad * 4] = o4;
    o4.x = f2bf(acc1[i][0] * dv1[0]);
    o4.y = f2bf(acc1[i][1] * dv1[1]);
    o4.z = f2bf(acc1[i][2] * dv1[2]);
    o4.w = f2bf(acc1[i][3] * dv1[3]);
    *(ushort4*)&yb[rowo + n0w + 16 + quad * 4] = o4;
  }
}

// ---------------------------------------------------------------------------
// PE-FUSED v1: dwconv3x3 + BN + add + TRANSPOSED write (replaces pe_kernel
// and transpose16_kernel). Block = (head h: 64 ch) x (200-pos chunk) x b.
// - Vh[64 d][7 rows x 56 + 2pad] staged from vp (d-fast => 1KB coalesced).
// - compute: 8-wide segments (v16 conv), read ybf_attn 16B, result into
//   Yt[d][200+8pad] (vector LDS writes, no conflict).
// - transposed write: yT[b][n][c] in 128B-contiguous runs.
// ---------------------------------------------------------------------------
__global__ __launch_bounds__(256) void pe_fused_kernel(
    const short* __restrict__ Ybf, const short* __restrict__ VP,
    const float* __restrict__ pw,
    const float* __restrict__ gamma, const float* __restrict__ beta,
    const float* __restrict__ mean, const float* __restrict__ var,
    short* __restrict__ YT) {
  __shared__ __align__(16) unsigned short Vh[64 * 394];  // [d][7*56 + 2 pad]
  __shared__ __align__(16) unsigned short Yt[64 * 208];  // [d][200 + 8 pad]
  __shared__ float wlds[576];
  __shared__ float invs[64], adds[64];

  const int t = threadIdx.x;
  const int h = blockIdx.x, nch = blockIdx.y, b = blockIdx.z;
  const int c0 = h * 64, n0 = nch * 200, r0 = nch * 5;

  for (int u = t; u < 576; u += 256) wlds[u] = pw[c0 * 9 + u];
  if (t < 64) {
    int c = c0 + t;
    float inv = gamma[c] * rsqrtf(var[c] + EPS);
    invs[t] = inv;
    adds[t] = beta[c] - mean[c] * inv;
  }
  const u16x8 z = {0, 0, 0, 0, 0, 0, 0, 0};
  for (int k = t; k < 3152; k += 256)        // 64*394 = 25216 = 3152*8
    *(u16x8*)&Vh[k * 8] = z;
  __syncthreads();

  const unsigned short* vpb = (const unsigned short*)VP + (size_t)(b * 8 + h) * 102400;
  for (int u = t; u < 2240; u += 256) {      // 64 d x 35 (7 rows x 5 chunks)
    const int d = u & 63, idx = u >> 6;
    const int rl = idx / 5, cb = idx % 5;
    const int rr = r0 - 1 + rl;
    if (rr >= 0 && rr < 40) {
      u16x8 ch8 = *(const u16x8*)(vpb + (size_t)(rr * 5 + cb) * 512 + d * 8);
      *(u16x8*)&Vh[d * 394 + rl * 56 + 8 + cb * 8] = ch8;
    }
  }
  __syncthreads();

  for (int u = t; u < 1600; u += 256) {      // 64 d x 25 segs (8 n each)
    const int d = u / 25, seg = u % 25;
    const int ry = seg / 5, cb8 = (seg % 5) * 8;
    const unsigned short* Vc = &Vh[d * 394 + (ry + 1) * 56 + 8 + cb8];
    const float* wk = &wlds[d * 9];
    float s[8];
#pragma unroll
    for (int jj = 0; jj < 8; ++jj) s[jj] = 0.f;
#pragma unroll
    for (int dy = 0; dy < 3; ++dy) {
      const unsigned short* Vr = Vc + (dy - 1) * 56;
      u16x8 cv = *(const u16x8*)Vr;
      float c[8];
#pragma unroll
      for (int jj = 0; jj < 8; ++jj) c[jj] = bf2f(cv[jj]);
      float left = bf2f(Vr[-1]);
      float right = bf2f(Vr[8]);
      const float w0 = wk[dy * 3 + 0], w1 = wk[dy * 3 + 1], w2 = wk[dy * 3 + 2];
      s[0] += w0 * left + w1 * c[0] + w2 * c[1];
#pragma unroll
      for (int jj = 1; jj < 7; ++jj)
        s[jj] += w0 * c[jj - 1] + w1 * c[jj] + w2 * c[jj + 1];
      s[7] += w0 * c[6] + w1 * c[7] + w2 * right;
    }
    const size_t idx = (size_t)(b * 512 + c0 + d) * 1600 + (r0 + ry) * 40 + cb8;
    u16x8 yv = *(const u16x8*)((const unsigned short*)Ybf + idx);
    union { unsigned short u[8]; u16x8 v; } o;
#pragma unroll
    for (int jj = 0; jj < 8; ++jj)
      o.u[jj] = f2bf(bf2f(yv[jj]) + s[jj] * invs[d] + adds[d]);
    *(u16x8*)&Yt[d * 208 + seg * 8] = o.v;
  }
  __syncthreads();

  for (int u = t; u < 1600; u += 256) {      // 200 n x 8 d-chunks
    const int j = u >> 3, ds8 = u & 7;
    union { unsigned short u[8]; u16x8 v; } o;
#pragma unroll
    for (int jj = 0; jj < 8; ++jj)
      o.u[jj] = Yt[(ds8 * 8 + jj) * 208 + j];
    *(u16x8*)((unsigned short*)YT +
        ((size_t)(b * 1600 + n0 + j)) * 512 + c0 + ds8 * 8) = o.v;
  }
}

// ---------------------------------------------------------------------------
// Proj GEMM v3 (m97 structure, unchanged).
// ---------------------------------------------------------------------------
__global__ __launch_bounds__(256) void proj_mfma_kernel(
    const short* __restrict__ YT, const short* __restrict__ WP,
    const float* __restrict__ gamma, const float* __restrict__ beta,
    const float* __restrict__ mean, const float* __restrict__ var,
    float* __restrict__ OUT) {
  __shared__ __align__(16) unsigned short As[64 * 32];
  __shared__ __align__(16) unsigned short Bs[128 * 32];

  const int t = threadIdx.x, w = t >> 6, lane = t & 63;
  const int quad = lane >> 4, l16 = lane & 15;
  const int wr = w >> 1, wc = w & 1;
  const int ngt = blockIdx.x;
  const int o0 = blockIdx.y * 64;
  const int ng0 = ngt * 128;

  const int srow = lane >> 2;
  const int sseg = (lane & 3) * 8;

  f32x4 acc[2][4];
#pragma unroll
  for (int mi = 0; mi < 2; ++mi)
#pragma unroll
    for (int nj = 0; nj < 4; ++nj) { acc[mi][nj][0]=0.f; acc[mi][nj][1]=0.f; acc[mi][nj][2]=0.f; acc[mi][nj][3]=0.f; }

  for (int kt = 0; kt < 16; ++kt) {
    const int c0 = kt * 32;
    if (kt) __syncthreads();
    {
      const int row = w * 16 + srow;
      gload_lds16(WP + (size_t)(o0 + row) * 512 + c0 + sseg, As + w * 512);
    }
#pragma unroll
    for (int r = 0; r < 2; ++r) {
      const int row = (r * 4 + w) * 16 + srow;
      gload_lds16(YT + (size_t)(ng0 + row) * 512 + c0 + sseg, Bs + (r * 4 + w) * 512);
    }
    __syncthreads();
    bf16x8 af[2], bfr[4];
#pragma unroll
    for (int i = 0; i < 2; ++i)
      af[i] = *(const bf16x8*)&As[(wr * 32 + i * 16 + l16) * 32 + quad * 8];
#pragma unroll
    for (int i = 0; i < 4; ++i)
      bfr[i] = *(const bf16x8*)&Bs[(wc * 64 + i * 16 + l16) * 32 + quad * 8];
#pragma unroll
    for (int mi = 0; mi < 2; ++mi)
#pragma unroll
      for (int nj = 0; nj < 4; ++nj)
        acc[mi][nj] = __builtin_amdgcn_mfma_f32_16x16x32_bf16(af[mi], bfr[nj], acc[mi][nj], 0, 0, 0);
  }

  const int ng_base = ng0 + wc * 64;
#pragma unroll
  for (int mi = 0; mi < 2; ++mi) {
    const int ob = o0 + wr * 32 + mi * 16 + quad * 4;
    float inv[4], add[4];
#pragma unroll
    for (int r = 0; r < 4; ++r) {
      inv[r] = gamma[ob + r] * rsqrtf(var[ob + r] + EPS);
      add[r] = beta[ob + r] - mean[ob + r] * inv[r];
    }
#pragma unroll
    for (int nj = 0; nj < 4; ++nj) {
      int ng = ng_base + nj * 16 + l16;
      int b = ng / 1600, n = ng - b * 1600;
#pragma unroll
      for (int r = 0; r < 4; ++r)
        OUT[((size_t)(b * 512 + ob + r)) * 1600 + n] = acc[mi][nj][r] * inv[r] + add[r];
    }
  }
}

// ---------------------------------------------------------------------------
extern "C" void kernel_launch(void* const* d_in, const int* in_sizes, int n_in,
                              void* d_out, int out_size, void* d_ws, size_t ws_size,
                              hipStream_t stream) {
  const float* x          = (const float*)d_in[0];
  const float* qkv_w      = (const float*)d_in[1];
  const float* qkv_gamma  = (const float*)d_in[2];
  const float* qkv_beta   = (const float*)d_in[3];
  const float* qkv_mean   = (const float*)d_in[4];
  const float* qkv_var    = (const float*)d_in[5];
  const float* pe_w       = (const float*)d_in[6];
  const float* pe_gamma   = (const float*)d_in[7];
  const float* pe_beta    = (const float*)d_in[8];
  const float* pe_mean    = (const float*)d_in[9];
  const float* pe_var     = (const float*)d_in[10];
  const float* proj_w     = (const float*)d_in[11];
  const float* proj_gamma = (const float*)d_in[12];
  const float* proj_beta  = (const float*)d_in[13];
  const float* proj_mean  = (const float*)d_in[14];
  const float* proj_var   = (const float*)d_in[15];
  float* out = (float*)d_out;

  float* ws_a = (float*)d_ws;
  short* ybf_attn = (short*)d_ws;                 // 6.55M shorts used
  short* vp   = ybf_attn + (size_t)6553600;       // dead half of 26.2MB region
  short* qT   = (short*)(ws_a + (size_t)6553600);
  short* kT   = qT + (size_t)3276800;
  short* vb_unused = kT + (size_t)3276800;        // (free region)
  short* xT   = vb_unused + (size_t)6553600;
  short* wq   = xT + (size_t)6553600;
  short* wp   = wq + (size_t)524288;
  short* yT   = xT;

  cast_w_kernel<<<768, 256, 0, stream>>>(qkv_w, proj_w, wq, wp);
  {
    dim3 grid(8, 25, 8), block(256);
    transpose_cast_kernel<<<grid, block, 0, stream>>>(x, xT);
  }
  {
    dim3 grid(100, 8), block(256);
    qkv_mfma_kernel<<<grid, block, 0, stream>>>(
        xT, wq, qkv_gamma, qkv_beta, qkv_mean, qkv_var, qT, kT, vp);
  }
  {
    dim3 grid(64, 13), block(256);
    attn_mfma_kernel<<<grid, block, 0, stream>>>(qT, kT, vp, ybf_attn);
  }
  {
    dim3 grid(8, 8, 8), block(256);
    pe_fused_kernel<<<grid, block, 0, stream>>>(
        ybf_attn, vp, pe_w, pe_gamma, pe_beta, pe_mean, pe_var, yT);
  }
  {
    dim3 grid(100, 8), block(256);
    proj_mfma_kernel<<<grid, block, 0, stream>>>(
        yT, wp, proj_gamma, proj_beta, proj_mean, proj_var, out);
  }
}